// Round 1
// baseline (480.554 us; speedup 1.0000x reference)
//
#include <hip/hip_runtime.h>

typedef __attribute__((ext_vector_type(4))) float f32x4;
typedef __attribute__((ext_vector_type(8))) short s16x8;

#define DEV static __device__ __forceinline__

DEV ushort f2bf(float f) {
    unsigned u = __float_as_uint(f);
    u += 0x7fffu + ((u >> 16) & 1u);   // round-to-nearest-even
    return (ushort)(u >> 16);
}
DEV float bf2f(ushort h) { return __uint_as_float(((unsigned)h) << 16); }

// ---------------- pack x (fp32 -> bf16) ----------------
__global__ void pack_x_k(const float* __restrict__ x, ushort* __restrict__ xb, int n4) {
    int stride = gridDim.x * blockDim.x;
    for (int i = blockIdx.x * blockDim.x + threadIdx.x; i < n4; i += stride) {
        float4 v = reinterpret_cast<const float4*>(x)[i];
        ushort4 o;
        o.x = f2bf(v.x); o.y = f2bf(v.y); o.z = f2bf(v.z); o.w = f2bf(v.w);
        reinterpret_cast<ushort4*>(xb)[i] = o;
    }
}

// ------------- transpose + pack weights: in fp32 [R][C] -> out bf16 [C][R] -------------
__global__ void trans_pack_k(const float* __restrict__ in, ushort* __restrict__ out, int R, int C) {
    __shared__ float tile[32][33];
    int bx = blockIdx.x * 32, by = blockIdx.y * 32;
    int tx = threadIdx.x, ty = threadIdx.y;
#pragma unroll
    for (int i = 0; i < 32; i += 8)
        tile[ty + i][tx] = in[(size_t)(by + ty + i) * C + bx + tx];
    __syncthreads();
#pragma unroll
    for (int i = 0; i < 32; i += 8)
        out[(size_t)(bx + ty + i) * R + by + tx] = f2bf(tile[tx][ty + i]);
}

// ---------------- main GEMM: C[M][Nn] = A[M][K](bf16) * Bt[Nn][K]^T (bf16), fp32 acc ----------------
// MODE 0: scatter qkv -> q/k/v buffers [b][h][n][64] bf16
// MODE 1: add bias, write fp32 to outf[M][Nn]
template <int MODE>
__global__ __launch_bounds__(256) void gemm_bt_k(
    const ushort* __restrict__ A, const ushort* __restrict__ Bt,
    int M, int Nn, int K,
    ushort* __restrict__ qo, ushort* __restrict__ ko, ushort* __restrict__ vo,
    const float* __restrict__ bias, float* __restrict__ outf)
{
    __shared__ __align__(16) ushort Al[128][40];  // +8 pad: bank-conflict-free frag reads
    __shared__ __align__(16) ushort Bl[128][40];
    const int t = threadIdx.x;
    const int w = t >> 6, lane = t & 63;
    const int wm = w >> 1, wn = w & 1;
    const int lrow = lane & 15, kh = lane >> 4;
    const int n0 = blockIdx.x * 128, m0 = blockIdx.y * 128;

    f32x4 acc[4][4] = {};

    for (int k0 = 0; k0 < K; k0 += 32) {
        __syncthreads();
#pragma unroll
        for (int j = 0; j < 2; ++j) {
            int idx = j * 256 + t;
            int row = idx >> 2, ch = idx & 3;
            *reinterpret_cast<int4*>(&Al[row][ch * 8]) =
                *reinterpret_cast<const int4*>(A + (size_t)(m0 + row) * K + k0 + ch * 8);
            *reinterpret_cast<int4*>(&Bl[row][ch * 8]) =
                *reinterpret_cast<const int4*>(Bt + (size_t)(n0 + row) * K + k0 + ch * 8);
        }
        __syncthreads();
        s16x8 af[4], bfr[4];
#pragma unroll
        for (int mi = 0; mi < 4; mi++)
            af[mi] = *reinterpret_cast<const s16x8*>(&Al[wm * 64 + mi * 16 + lrow][kh * 8]);
#pragma unroll
        for (int ni = 0; ni < 4; ni++)
            bfr[ni] = *reinterpret_cast<const s16x8*>(&Bl[wn * 64 + ni * 16 + lrow][kh * 8]);
#pragma unroll
        for (int mi = 0; mi < 4; mi++)
#pragma unroll
            for (int ni = 0; ni < 4; ni++)
                acc[mi][ni] = __builtin_amdgcn_mfma_f32_16x16x32_bf16(af[mi], bfr[ni], acc[mi][ni], 0, 0, 0);
    }

    // C/D layout (verified m89): col = lane&15, row = (lane>>4)*4 + reg
    if (MODE == 0) {
#pragma unroll
        for (int mi = 0; mi < 4; mi++)
#pragma unroll
            for (int ni = 0; ni < 4; ni++) {
                int e = n0 + wn * 64 + ni * 16 + lrow;       // qkv column in [0,3072)
                int which = e >> 10;
                int h = (e >> 6) & 15;
                int d = e & 63;
                ushort* dst = (which == 0) ? qo : (which == 1) ? ko : vo;
#pragma unroll
                for (int j = 0; j < 4; j++) {
                    int m = m0 + wm * 64 + mi * 16 + kh * 4 + j;
                    int b = m >> 12, ns = m & 4095;
                    dst[((((size_t)b * 16 + h) * 4096) + ns) * 64 + d] = f2bf(acc[mi][ni][j]);
                }
            }
    } else {
#pragma unroll
        for (int mi = 0; mi < 4; mi++)
#pragma unroll
            for (int ni = 0; ni < 4; ni++) {
                int e = n0 + wn * 64 + ni * 16 + lrow;
                float bv = bias[e];
#pragma unroll
                for (int j = 0; j < 4; j++) {
                    int m = m0 + wm * 64 + mi * 16 + kh * 4 + j;
                    outf[(size_t)m * Nn + e] = acc[mi][ni][j] + bv;
                }
            }
    }
}

// ---------------- per-head LayerNorm over last dim (64), in place, wave per row ----------------
__global__ void ln_k(ushort* __restrict__ kk, ushort* __restrict__ vv,
                     const float* __restrict__ gk, const float* __restrict__ bk,
                     const float* __restrict__ gv, const float* __restrict__ bv)
{
    const int ROWS = 4 * 16 * 4096;
    int gtid = blockIdx.x * blockDim.x + threadIdx.x;
    int wid = gtid >> 6;
    int lane = threadIdx.x & 63;
    int nw = (gridDim.x * blockDim.x) >> 6;
    for (int r = wid; r < 2 * ROWS; r += nw) {
        ushort* buf; const float *g, *bta; int rr = r;
        if (r < ROWS) { buf = kk; g = gk; bta = bk; }
        else          { rr = r - ROWS; buf = vv; g = gv; bta = bv; }
        int h = (rr >> 12) & 15;
        ushort* p = buf + (size_t)rr * 64;
        float x = bf2f(p[lane]);
        float s = x;
#pragma unroll
        for (int o = 32; o > 0; o >>= 1) s += __shfl_xor(s, o, 64);
        float mu = s * (1.f / 64.f);
        float dx = x - mu;
        float s2 = dx * dx;
#pragma unroll
        for (int o = 32; o > 0; o >>= 1) s2 += __shfl_xor(s2, o, 64);
        float var = s2 * (1.f / 64.f);
        float y = dx * rsqrtf(var + 1e-5f) * g[h * 64 + lane] + bta[h * 64 + lane];
        p[lane] = f2bf(y);
    }
}

// ---------------- scores[bh][d][e] = sum_n kn[n,d]*vn[n,e] / 4096, fp32 atomics ----------------
__global__ __launch_bounds__(256) void scores_k(const ushort* __restrict__ kn,
                                                const ushort* __restrict__ vn,
                                                float* __restrict__ sc)
{
    __shared__ __align__(16) ushort ks[128][64];
    __shared__ __align__(16) ushort vs[128][64];
    int bh = blockIdx.y;
    int t = threadIdx.x;
    int d = t & 63, eg = t >> 6;
    const ushort* kb = kn + (size_t)bh * 4096 * 64;
    const ushort* vb = vn + (size_t)bh * 4096 * 64;
    float acc[16];
#pragma unroll
    for (int i = 0; i < 16; i++) acc[i] = 0.f;
    int c0 = blockIdx.x * 512;
    for (int cc = c0; cc < c0 + 512; cc += 128) {
        __syncthreads();
        for (int i = t; i < 1024; i += 256) {
            reinterpret_cast<int4*>(ks)[i] = *reinterpret_cast<const int4*>(kb + (size_t)cc * 64 + i * 8);
            reinterpret_cast<int4*>(vs)[i] = *reinterpret_cast<const int4*>(vb + (size_t)cc * 64 + i * 8);
        }
        __syncthreads();
        for (int n = 0; n < 128; ++n) {
            float kval = bf2f(ks[n][d]);
            uint4 v0 = *reinterpret_cast<const uint4*>(&vs[n][eg * 16]);
            uint4 v1 = *reinterpret_cast<const uint4*>(&vs[n][eg * 16 + 8]);
            unsigned vvv[8] = {v0.x, v0.y, v0.z, v0.w, v1.x, v1.y, v1.z, v1.w};
#pragma unroll
            for (int i = 0; i < 8; i++) {
                float lo = __uint_as_float(vvv[i] << 16);
                float hi = __uint_as_float(vvv[i] & 0xffff0000u);
                acc[2 * i]     = fmaf(kval, lo, acc[2 * i]);
                acc[2 * i + 1] = fmaf(kval, hi, acc[2 * i + 1]);
            }
        }
    }
    const float scale = 1.f / 4096.f;
#pragma unroll
    for (int i = 0; i < 16; i++)
        atomicAdd(&sc[(size_t)bh * 4096 + d * 64 + eg * 16 + i], acc[i] * scale);
}

// ---------------- scores fp32 [bh][d][e] -> scoresT bf16 [bh][e][d] ----------------
__global__ void pack_sT_k(const float* __restrict__ sc, ushort* __restrict__ sT) {
    int bh = blockIdx.x, t = threadIdx.x;
#pragma unroll
    for (int i = 0; i < 16; i++) {
        int o = t * 16 + i;
        int e = o >> 6, dd = o & 63;
        sT[(size_t)bh * 4096 + o] = f2bf(sc[(size_t)bh * 4096 + (size_t)dd * 64 + e]);
    }
}

// ---------------- out_mid[b][n][h*64+e] = sum_d q[bh][n][d] * scores[d][e] ----------------
__global__ __launch_bounds__(256) void gemm_qs_k(const ushort* __restrict__ q,
                                                 const ushort* __restrict__ sT,
                                                 ushort* __restrict__ om)
{
    __shared__ __align__(16) ushort sl[64][72];  // padded rows (144B): 2-way banks only
    int bh = blockIdx.y;
    int bb = bh >> 4, h = bh & 15;
    int nt = blockIdx.x;
    int t = threadIdx.x;
    for (int i = t; i < 512; i += 256) {
        int e = i >> 3, c = i & 7;
        *reinterpret_cast<int4*>(&sl[e][c * 8]) = reinterpret_cast<const int4*>(sT + (size_t)bh * 4096)[i];
    }
    __syncthreads();
    int w = t >> 6, lane = t & 63;
    int lrow = lane & 15, kh = lane >> 4;
    const ushort* qb = q + ((size_t)bh * 4096 + nt * 256 + (size_t)w * 64) * 64;
    f32x4 acc[4][4] = {};
#pragma unroll
    for (int ks = 0; ks < 2; ++ks) {
        s16x8 af[4], bfr[4];
#pragma unroll
        for (int ni = 0; ni < 4; ni++)
            bfr[ni] = *reinterpret_cast<const s16x8*>(&sl[ni * 16 + lrow][ks * 32 + kh * 8]);
#pragma unroll
        for (int mi = 0; mi < 4; mi++)
            af[mi] = *reinterpret_cast<const s16x8*>(qb + (size_t)(mi * 16 + lrow) * 64 + ks * 32 + kh * 8);
#pragma unroll
        for (int mi = 0; mi < 4; mi++)
#pragma unroll
            for (int ni = 0; ni < 4; ni++)
                acc[mi][ni] = __builtin_amdgcn_mfma_f32_16x16x32_bf16(af[mi], bfr[ni], acc[mi][ni], 0, 0, 0);
    }
#pragma unroll
    for (int mi = 0; mi < 4; mi++)
#pragma unroll
        for (int ni = 0; ni < 4; ni++)
#pragma unroll
            for (int j = 0; j < 4; j++) {
                int n = nt * 256 + w * 64 + mi * 16 + kh * 4 + j;
                int e = ni * 16 + lrow;
                om[((size_t)bb * 4096 + n) * 1024 + h * 64 + e] = f2bf(acc[mi][ni][j]);
            }
}

extern "C" void kernel_launch(void* const* d_in, const int* in_sizes, int n_in,
                              void* d_out, int out_size, void* d_ws, size_t ws_size,
                              hipStream_t stream)
{
    const float* x       = (const float*)d_in[0];
    const float* w_qkv   = (const float*)d_in[1];
    const float* gamma_k = (const float*)d_in[2];
    const float* beta_k  = (const float*)d_in[3];
    const float* gamma_v = (const float*)d_in[4];
    const float* beta_v  = (const float*)d_in[5];
    const float* w_out   = (const float*)d_in[6];
    const float* b_out   = (const float*)d_in[7];
    float* out = (float*)d_out;

    char* ws = (char*)d_ws;
    const size_t MB = 1024 * 1024;
    ushort* xb    = (ushort*)(ws);              // 32MB (reused as out_mid later)
    ushort* wqkvT = (ushort*)(ws + 32 * MB);    // 6MB   [3072][1024]
    ushort* woutT = (ushort*)(ws + 38 * MB);    // 2MB   [1024][1024]
    ushort* qb    = (ushort*)(ws + 40 * MB);    // 32MB  [b][h][n][64]
    ushort* kb    = (ushort*)(ws + 72 * MB);    // 32MB
    ushort* vb    = (ushort*)(ws + 104 * MB);   // 32MB
    float*  sc    = (float*)(ws + 136 * MB);    // 1MB   [bh][d][e]
    ushort* sT    = (ushort*)(ws + 137 * MB);   // 0.5MB [bh][e][d]
    ushort* om    = xb;                         // out_mid [b][n][1024] bf16 (xb dead after GEMM1)

    pack_x_k<<<4096, 256, 0, stream>>>(x, xb, 16384 * 1024 / 4);
    trans_pack_k<<<dim3(96, 32), dim3(32, 8), 0, stream>>>(w_qkv, wqkvT, 1024, 3072);
    trans_pack_k<<<dim3(32, 32), dim3(32, 8), 0, stream>>>(w_out, woutT, 1024, 1024);
    gemm_bt_k<0><<<dim3(24, 128), 256, 0, stream>>>(xb, wqkvT, 16384, 3072, 1024,
                                                    qb, kb, vb, nullptr, nullptr);
    ln_k<<<2048, 256, 0, stream>>>(kb, vb, gamma_k, beta_k, gamma_v, beta_v);
    hipMemsetAsync(sc, 0, 64 * 4096 * sizeof(float), stream);
    scores_k<<<dim3(8, 64), 256, 0, stream>>>(kb, vb, sc);
    pack_sT_k<<<64, 256, 0, stream>>>(sc, sT);
    gemm_qs_k<<<dim3(16, 64), 256, 0, stream>>>(qb, sT, om);
    gemm_bt_k<1><<<dim3(8, 128), 256, 0, stream>>>(om, woutT, 16384, 1024, 1024,
                                                   nullptr, nullptr, nullptr, b_out, out);
}

// Round 2
// 421.816 us; speedup vs baseline: 1.1393x; 1.1393x over previous
//
#include <hip/hip_runtime.h>

typedef __attribute__((ext_vector_type(4))) float f32x4;
typedef __attribute__((ext_vector_type(8))) short s16x8;

#define DEV static __device__ __forceinline__

typedef __attribute__((address_space(3))) void lds_t;
typedef __attribute__((address_space(1))) void gbl_t;

DEV void gload_lds16(const void* g, void* l) {
    __builtin_amdgcn_global_load_lds((gbl_t*)g, (lds_t*)l, 16, 0, 0);
}

DEV ushort f2bf(float f) {
    unsigned u = __float_as_uint(f);
    u += 0x7fffu + ((u >> 16) & 1u);   // round-to-nearest-even
    return (ushort)(u >> 16);
}
DEV float bf2f(ushort h) { return __uint_as_float(((unsigned)h) << 16); }

// ---------------- pack x (fp32 -> bf16) ----------------
__global__ void pack_x_k(const float* __restrict__ x, ushort* __restrict__ xb, int n4) {
    int stride = gridDim.x * blockDim.x;
    for (int i = blockIdx.x * blockDim.x + threadIdx.x; i < n4; i += stride) {
        float4 v = reinterpret_cast<const float4*>(x)[i];
        ushort4 o;
        o.x = f2bf(v.x); o.y = f2bf(v.y); o.z = f2bf(v.z); o.w = f2bf(v.w);
        reinterpret_cast<ushort4*>(xb)[i] = o;
    }
}

// ------------- transpose + pack weights: in fp32 [R][C] -> out bf16 [C][R] -------------
__global__ void trans_pack_k(const float* __restrict__ in, ushort* __restrict__ out, int R, int C) {
    __shared__ float tile[32][33];
    int bx = blockIdx.x * 32, by = blockIdx.y * 32;
    int tx = threadIdx.x, ty = threadIdx.y;
#pragma unroll
    for (int i = 0; i < 32; i += 8)
        tile[ty + i][tx] = in[(size_t)(by + ty + i) * C + bx + tx];
    __syncthreads();
#pragma unroll
    for (int i = 0; i < 32; i += 8)
        out[(size_t)(bx + ty + i) * R + by + tx] = f2bf(tile[tx][ty + i]);
}

// ---------------- main GEMM: C[M][Nn] = A[M][K](bf16) * Bt[Nn][K]^T (bf16), fp32 acc ----------------
// global_load_lds width-16 staging into linear LDS [128][32] (m97 structure).
// MODE 0: col<1024 -> q flat [m][1024]; cols 1024..3071 -> per-head LayerNorm fused, scatter
//         to k/v buffers [b][h][n][64] bf16.
// MODE 1: add bias, write fp32 to outf[M][Nn]; Bt selected per-b via b_stride.
template <int MODE>
__global__ __launch_bounds__(256) void gemm_bt_k(
    const ushort* __restrict__ A, const ushort* __restrict__ Bt,
    int Nn, int K, size_t b_stride,
    ushort* __restrict__ qo, ushort* __restrict__ ko, ushort* __restrict__ vo,
    const float* __restrict__ gk, const float* __restrict__ bk,
    const float* __restrict__ gv, const float* __restrict__ bv,
    const float* __restrict__ bias, float* __restrict__ outf)
{
    __shared__ __align__(16) ushort Al[128 * 32];
    __shared__ __align__(16) ushort Bl[128 * 32];
    const int t = threadIdx.x;
    const int w = t >> 6, lane = t & 63;
    const int wm = w >> 1, wn = w & 1;
    const int lrow = lane & 15, kh = lane >> 4;
    const int n0 = blockIdx.x * 128, m0 = blockIdx.y * 128;

    const ushort* Bte = Bt + (size_t)(m0 >> 12) * b_stride;

    // staging geometry: wave w, call c in {0,1}: elem base = w*1024 + c*512, lane covers 8 elems
    const int srow0 = w * 32 + (lane >> 2);     // c=0 row
    const int scol = (lane & 3) * 8;

    f32x4 acc[4][4] = {};

    for (int k0 = 0; k0 < K; k0 += 32) {
        __syncthreads();
        gload_lds16(A   + (size_t)(m0 + srow0)      * K + k0 + scol, Al + w * 1024);
        gload_lds16(Bte + (size_t)(n0 + srow0)      * K + k0 + scol, Bl + w * 1024);
        gload_lds16(A   + (size_t)(m0 + srow0 + 16) * K + k0 + scol, Al + w * 1024 + 512);
        gload_lds16(Bte + (size_t)(n0 + srow0 + 16) * K + k0 + scol, Bl + w * 1024 + 512);
        __syncthreads();
        s16x8 af[4], bfr[4];
#pragma unroll
        for (int mi = 0; mi < 4; mi++)
            af[mi] = *reinterpret_cast<const s16x8*>(&Al[(wm * 64 + mi * 16 + lrow) * 32 + kh * 8]);
#pragma unroll
        for (int ni = 0; ni < 4; ni++)
            bfr[ni] = *reinterpret_cast<const s16x8*>(&Bl[(wn * 64 + ni * 16 + lrow) * 32 + kh * 8]);
#pragma unroll
        for (int mi = 0; mi < 4; mi++)
#pragma unroll
            for (int ni = 0; ni < 4; ni++)
                acc[mi][ni] = __builtin_amdgcn_mfma_f32_16x16x32_bf16(af[mi], bfr[ni], acc[mi][ni], 0, 0, 0);
    }

    // C/D layout (verified m89): col = lane&15, row = (lane>>4)*4 + reg
    if (MODE == 0) {
        const int e0 = n0 + wn * 64;        // wave's aligned 64-col group == one head
        const int which = e0 >> 10;         // 0=q, 1=k, 2=v
        const int h = (e0 >> 6) & 15;
        if (which == 0) {
#pragma unroll
            for (int mi = 0; mi < 4; mi++)
#pragma unroll
                for (int ni = 0; ni < 4; ni++) {
                    int e = e0 + ni * 16 + lrow;
#pragma unroll
                    for (int j = 0; j < 4; j++) {
                        int m = m0 + wm * 64 + mi * 16 + kh * 4 + j;
                        qo[(size_t)m * 1024 + e] = f2bf(acc[mi][ni][j]);
                    }
                }
        } else {
            const float* g  = (which == 1) ? gk : gv;
            const float* bb = (which == 1) ? bk : bv;
            ushort* dst     = (which == 1) ? ko : vo;
            float gr[4], br[4];
#pragma unroll
            for (int ni = 0; ni < 4; ni++) {
                gr[ni] = g[h * 64 + ni * 16 + lrow];
                br[ni] = bb[h * 64 + ni * 16 + lrow];
            }
#pragma unroll
            for (int mi = 0; mi < 4; mi++)
#pragma unroll
                for (int j = 0; j < 4; j++) {
                    float s = acc[mi][0][j] + acc[mi][1][j] + acc[mi][2][j] + acc[mi][3][j];
                    s += __shfl_xor(s, 1, 64);
                    s += __shfl_xor(s, 2, 64);
                    s += __shfl_xor(s, 4, 64);
                    s += __shfl_xor(s, 8, 64);
                    float mu = s * (1.f / 64.f);
                    float t2 = 0.f;
#pragma unroll
                    for (int ni = 0; ni < 4; ni++) {
                        float dd = acc[mi][ni][j] - mu;
                        t2 += dd * dd;
                    }
                    t2 += __shfl_xor(t2, 1, 64);
                    t2 += __shfl_xor(t2, 2, 64);
                    t2 += __shfl_xor(t2, 4, 64);
                    t2 += __shfl_xor(t2, 8, 64);
                    float inv = rsqrtf(t2 * (1.f / 64.f) + 1e-5f);
                    int m = m0 + wm * 64 + mi * 16 + kh * 4 + j;
                    int b = m >> 12, ns = m & 4095;
                    size_t base = ((((size_t)b * 16 + h) * 4096) + ns) * 64;
#pragma unroll
                    for (int ni = 0; ni < 4; ni++) {
                        float y = (acc[mi][ni][j] - mu) * inv * gr[ni] + br[ni];
                        dst[base + ni * 16 + lrow] = f2bf(y);
                    }
                }
        }
    } else {
#pragma unroll
        for (int mi = 0; mi < 4; mi++)
#pragma unroll
            for (int ni = 0; ni < 4; ni++) {
                int e = n0 + wn * 64 + ni * 16 + lrow;
                float bv2 = bias[e];
#pragma unroll
                for (int j = 0; j < 4; j++) {
                    int m = m0 + wm * 64 + mi * 16 + kh * 4 + j;
                    outf[(size_t)m * Nn + e] = acc[mi][ni][j] + bv2;
                }
            }
    }
}

// ---------------- scores[bh][d][e] = sum_n kn[n,d]*vn[n,e] / 4096, fp32 atomics ----------------
__global__ __launch_bounds__(256) void scores_k(const ushort* __restrict__ kn,
                                                const ushort* __restrict__ vn,
                                                float* __restrict__ sc)
{
    __shared__ __align__(16) ushort ks[128][64];
    __shared__ __align__(16) ushort vs[128][64];
    int bh = blockIdx.y;
    int t = threadIdx.x;
    int d = t & 63, eg = t >> 6;
    const ushort* kb = kn + (size_t)bh * 4096 * 64;
    const ushort* vb = vn + (size_t)bh * 4096 * 64;
    float acc[16];
#pragma unroll
    for (int i = 0; i < 16; i++) acc[i] = 0.f;
    int c0 = blockIdx.x * 512;
    for (int cc = c0; cc < c0 + 512; cc += 128) {
        __syncthreads();
        for (int i = t; i < 1024; i += 256) {
            reinterpret_cast<int4*>(ks)[i] = *reinterpret_cast<const int4*>(kb + (size_t)cc * 64 + i * 8);
            reinterpret_cast<int4*>(vs)[i] = *reinterpret_cast<const int4*>(vb + (size_t)cc * 64 + i * 8);
        }
        __syncthreads();
        for (int n = 0; n < 128; ++n) {
            float kval = bf2f(ks[n][d]);
            uint4 v0 = *reinterpret_cast<const uint4*>(&vs[n][eg * 16]);
            uint4 v1 = *reinterpret_cast<const uint4*>(&vs[n][eg * 16 + 8]);
            unsigned vvv[8] = {v0.x, v0.y, v0.z, v0.w, v1.x, v1.y, v1.z, v1.w};
#pragma unroll
            for (int i = 0; i < 8; i++) {
                float lo = __uint_as_float(vvv[i] << 16);
                float hi = __uint_as_float(vvv[i] & 0xffff0000u);
                acc[2 * i]     = fmaf(kval, lo, acc[2 * i]);
                acc[2 * i + 1] = fmaf(kval, hi, acc[2 * i + 1]);
            }
        }
    }
    const float scale = 1.f / 4096.f;
#pragma unroll
    for (int i = 0; i < 16; i++)
        atomicAdd(&sc[(size_t)bh * 4096 + d * 64 + eg * 16 + i], acc[i] * scale);
}

// -------- W'T[b][f][h*64+d] = sum_e woutT[f][h*64+e] * sc[b*16+h][d][e], bf16 out --------
__global__ __launch_bounds__(256) void wprime_k(const float* __restrict__ sc,
                                                const ushort* __restrict__ woutT,
                                                ushort* __restrict__ wpT)
{
    __shared__ float scl[64][65];      // [e][d], padded: conflict-free
    __shared__ ushort wl[128][72];     // [f_local][e], padded
    int bh = blockIdx.y;
    int b = bh >> 4, h = bh & 15;
    int f0 = blockIdx.x * 128;
    int t = threadIdx.x;
    for (int i = t; i < 4096; i += 256) {
        int d2 = i >> 6, e = i & 63;
        scl[e][d2] = sc[(size_t)bh * 4096 + i];
    }
    for (int i = t; i < 1024; i += 256) {
        int fl = i >> 3, c = i & 7;
        *reinterpret_cast<int4*>(&wl[fl][c * 8]) =
            *reinterpret_cast<const int4*>(woutT + (size_t)(f0 + fl) * 1024 + h * 64 + c * 8);
    }
    __syncthreads();
    int dd = (t & 7) * 8;
    int fl0 = t >> 3;
#pragma unroll
    for (int fi = 0; fi < 4; ++fi) {
        int fl = fi * 32 + fl0;
        float acc[8] = {};
        for (int e = 0; e < 64; ++e) {
            float wv = bf2f(wl[fl][e]);
#pragma unroll
            for (int i = 0; i < 8; ++i)
                acc[i] = fmaf(wv, scl[e][dd + i], acc[i]);
        }
        ushort4 o0, o1;
        o0.x = f2bf(acc[0]); o0.y = f2bf(acc[1]); o0.z = f2bf(acc[2]); o0.w = f2bf(acc[3]);
        o1.x = f2bf(acc[4]); o1.y = f2bf(acc[5]); o1.z = f2bf(acc[6]); o1.w = f2bf(acc[7]);
        ushort* op = wpT + ((size_t)b * 1024 + f0 + fl) * 1024 + h * 64 + dd;
        *reinterpret_cast<ushort4*>(op) = o0;
        *reinterpret_cast<ushort4*>(op + 4) = o1;
    }
}

extern "C" void kernel_launch(void* const* d_in, const int* in_sizes, int n_in,
                              void* d_out, int out_size, void* d_ws, size_t ws_size,
                              hipStream_t stream)
{
    const float* x       = (const float*)d_in[0];
    const float* w_qkv   = (const float*)d_in[1];
    const float* gamma_k = (const float*)d_in[2];
    const float* beta_k  = (const float*)d_in[3];
    const float* gamma_v = (const float*)d_in[4];
    const float* beta_v  = (const float*)d_in[5];
    const float* w_out   = (const float*)d_in[6];
    const float* b_out   = (const float*)d_in[7];
    float* out = (float*)d_out;

    char* ws = (char*)d_ws;
    const size_t MB = 1024 * 1024;
    ushort* xb    = (ushort*)(ws);              // 32MB; dead after GEMM1 -> reused as wpT
    ushort* wpT   = (ushort*)(ws);              // 8MB  [b][f][h*64+d] bf16
    ushort* wqkvT = (ushort*)(ws + 32 * MB);    // 6MB  [3072][1024]
    ushort* woutT = (ushort*)(ws + 38 * MB);    // 2MB  [1024][1024]
    ushort* qf    = (ushort*)(ws + 40 * MB);    // 32MB [m][1024] (q flat)
    ushort* kb    = (ushort*)(ws + 72 * MB);    // 32MB [b][h][n][64]
    ushort* vb    = (ushort*)(ws + 104 * MB);   // 32MB
    float*  sc    = (float*)(ws + 136 * MB);    // 1MB  [bh][d][e]

    pack_x_k<<<4096, 256, 0, stream>>>(x, xb, 16384 * 1024 / 4);
    trans_pack_k<<<dim3(96, 32), dim3(32, 8), 0, stream>>>(w_qkv, wqkvT, 1024, 3072);
    trans_pack_k<<<dim3(32, 32), dim3(32, 8), 0, stream>>>(w_out, woutT, 1024, 1024);
    // GEMM1 + fused per-head LN + scatter
    gemm_bt_k<0><<<dim3(24, 128), 256, 0, stream>>>(xb, wqkvT, 3072, 1024, (size_t)0,
                                                    qf, kb, vb,
                                                    gamma_k, beta_k, gamma_v, beta_v,
                                                    nullptr, nullptr);
    hipMemsetAsync(sc, 0, 64 * 4096 * sizeof(float), stream);
    scores_k<<<dim3(8, 64), 256, 0, stream>>>(kb, vb, sc);
    wprime_k<<<dim3(8, 64), 256, 0, stream>>>(sc, woutT, wpT);
    // out = q_flat · W'T(b) + bias
    gemm_bt_k<1><<<dim3(8, 128), 256, 0, stream>>>(qf, wpT, 1024, 1024, (size_t)(1024 * 1024),
                                                   nullptr, nullptr, nullptr,
                                                   nullptr, nullptr, nullptr, nullptr,
                                                   b_out, out);
}

// Round 3
// 390.691 us; speedup vs baseline: 1.2300x; 1.0797x over previous
//
#include <hip/hip_runtime.h>

typedef __attribute__((ext_vector_type(4))) float f32x4;
typedef __attribute__((ext_vector_type(8))) short s16x8;

#define DEV static __device__ __forceinline__

typedef __attribute__((address_space(3))) void lds_t;
typedef __attribute__((address_space(1))) void gbl_t;

DEV void gload_lds16(const void* g, void* l) {
    __builtin_amdgcn_global_load_lds((gbl_t*)g, (lds_t*)l, 16, 0, 0);
}

DEV ushort f2bf(float f) {
    unsigned u = __float_as_uint(f);
    u += 0x7fffu + ((u >> 16) & 1u);   // round-to-nearest-even
    return (ushort)(u >> 16);
}
DEV float bf2f(ushort h) { return __uint_as_float(((unsigned)h) << 16); }

// ---------------- pack x (fp32 -> bf16) ----------------
__global__ void pack_x_k(const float* __restrict__ x, ushort* __restrict__ xb, int n4) {
    int stride = gridDim.x * blockDim.x;
    for (int i = blockIdx.x * blockDim.x + threadIdx.x; i < n4; i += stride) {
        float4 v = reinterpret_cast<const float4*>(x)[i];
        ushort4 o;
        o.x = f2bf(v.x); o.y = f2bf(v.y); o.z = f2bf(v.z); o.w = f2bf(v.w);
        reinterpret_cast<ushort4*>(xb)[i] = o;
    }
}

// ---- pack Wq slice (no transpose): wqb[c][d'] = bf16(w_qkv[c][d']), d'<1024, row stride 3072 ----
__global__ void pack_wq_k(const float* __restrict__ w, ushort* __restrict__ o) {
    int i = blockIdx.x * 256 + threadIdx.x;   // over 1024*256 float4 groups
    int r = i >> 8, c4 = i & 255;
    float4 v = *reinterpret_cast<const float4*>(w + (size_t)r * 3072 + c4 * 4);
    ushort4 u;
    u.x = f2bf(v.x); u.y = f2bf(v.y); u.z = f2bf(v.z); u.w = f2bf(v.w);
    *reinterpret_cast<ushort4*>(o + (size_t)r * 1024 + c4 * 4) = u;
}

// ------- transpose + pack: in fp32 [R][C], cols col0.., -> out bf16 [C-col0][R] -------
__global__ void trans_pack_k(const float* __restrict__ in, ushort* __restrict__ out,
                             int R, int C, int col0) {
    __shared__ float tile[32][33];
    int bx = col0 + blockIdx.x * 32, by = blockIdx.y * 32;
    int tx = threadIdx.x, ty = threadIdx.y;
#pragma unroll
    for (int i = 0; i < 32; i += 8)
        tile[ty + i][tx] = in[(size_t)(by + ty + i) * C + bx + tx];
    __syncthreads();
#pragma unroll
    for (int i = 0; i < 32; i += 8)
        out[(size_t)(bx - col0 + ty + i) * R + by + tx] = f2bf(tile[tx][ty + i]);
}

// ---------------- main GEMM: C[M][Nn] = A[M][K](bf16) * Bt[Nn][K]^T (bf16), fp32 acc ----------------
// global_load_lds width-16 staging, linear LDS [128][32] (m97 structure), XCD-chunked swizzle.
// MODE 0: per-head LayerNorm fused on every 64-col group; scatter to k/v [b][h][n][64] bf16.
// MODE 1: add bias, write fp32 to outf[M][Nn]; Bt selected per-b via b_stride (b = m0>>12).
// MODE 2: bf16 out to qo (per-b via blockIdx.z: A += z*a_bstride, qo += z*2^20), no swizzle.
template <int MODE>
__global__ __launch_bounds__(256) void gemm_bt_k(
    const ushort* __restrict__ A, const ushort* __restrict__ Bt,
    int Nn, int K, int col0, size_t b_stride, size_t a_bstride,
    ushort* __restrict__ qo, ushort* __restrict__ ko, ushort* __restrict__ vo,
    const float* __restrict__ gk, const float* __restrict__ bk,
    const float* __restrict__ gv, const float* __restrict__ bv,
    const float* __restrict__ bias, float* __restrict__ outf)
{
    __shared__ __align__(16) ushort Al[128 * 32];
    __shared__ __align__(16) ushort Bl[128 * 32];
    const int t = threadIdx.x;
    const int w = t >> 6, lane = t & 63;
    const int wm = w >> 1, wn = w & 1;
    const int lrow = lane & 15, kh = lane >> 4;

    int n0, m0;
    if (MODE == 2) {
        n0 = blockIdx.x * 128; m0 = blockIdx.y * 128;
    } else {
        // bijective XCD-chunked swizzle (grid total % 8 == 0)
        int bid = blockIdx.y * gridDim.x + blockIdx.x;
        int C8 = (gridDim.x * gridDim.y) >> 3;
        int nid = (bid & 7) * C8 + (bid >> 3);
        n0 = (nid % gridDim.x) * 128;
        m0 = (nid / gridDim.x) * 128;
    }

    const ushort* Ae  = (MODE == 2) ? A + blockIdx.z * a_bstride : A;
    const ushort* Bte = (MODE == 1) ? Bt + (size_t)(m0 >> 12) * b_stride : Bt;

    const int srow0 = w * 32 + (lane >> 2);
    const int scol = (lane & 3) * 8;

    f32x4 acc[4][4] = {};

    for (int k0 = 0; k0 < K; k0 += 32) {
        __syncthreads();
        gload_lds16(Ae  + (size_t)(m0 + srow0)      * K + k0 + scol, Al + w * 1024);
        gload_lds16(Bte + (size_t)(n0 + srow0)      * K + k0 + scol, Bl + w * 1024);
        gload_lds16(Ae  + (size_t)(m0 + srow0 + 16) * K + k0 + scol, Al + w * 1024 + 512);
        gload_lds16(Bte + (size_t)(n0 + srow0 + 16) * K + k0 + scol, Bl + w * 1024 + 512);
        __syncthreads();
        s16x8 af[4], bfr[4];
#pragma unroll
        for (int mi = 0; mi < 4; mi++)
            af[mi] = *reinterpret_cast<const s16x8*>(&Al[(wm * 64 + mi * 16 + lrow) * 32 + kh * 8]);
#pragma unroll
        for (int ni = 0; ni < 4; ni++)
            bfr[ni] = *reinterpret_cast<const s16x8*>(&Bl[(wn * 64 + ni * 16 + lrow) * 32 + kh * 8]);
#pragma unroll
        for (int mi = 0; mi < 4; mi++)
#pragma unroll
            for (int ni = 0; ni < 4; ni++)
                acc[mi][ni] = __builtin_amdgcn_mfma_f32_16x16x32_bf16(af[mi], bfr[ni], acc[mi][ni], 0, 0, 0);
    }

    // C/D layout (verified m89): col = lane&15, row = (lane>>4)*4 + reg
    if (MODE == 0) {
        const int e0 = col0 + n0 + wn * 64;   // aligned 64-col group == one head
        const int which = e0 >> 10;           // 1=k, 2=v
        const int h = (e0 >> 6) & 15;
        const float* g  = (which == 1) ? gk : gv;
        const float* bb = (which == 1) ? bk : bv;
        ushort* dst     = (which == 1) ? ko : vo;
        float gr[4], br[4];
#pragma unroll
        for (int ni = 0; ni < 4; ni++) {
            gr[ni] = g[h * 64 + ni * 16 + lrow];
            br[ni] = bb[h * 64 + ni * 16 + lrow];
        }
#pragma unroll
        for (int mi = 0; mi < 4; mi++)
#pragma unroll
            for (int j = 0; j < 4; j++) {
                float s = acc[mi][0][j] + acc[mi][1][j] + acc[mi][2][j] + acc[mi][3][j];
                s += __shfl_xor(s, 1, 64);
                s += __shfl_xor(s, 2, 64);
                s += __shfl_xor(s, 4, 64);
                s += __shfl_xor(s, 8, 64);
                float mu = s * (1.f / 64.f);
                float t2 = 0.f;
#pragma unroll
                for (int ni = 0; ni < 4; ni++) {
                    float dd = acc[mi][ni][j] - mu;
                    t2 += dd * dd;
                }
                t2 += __shfl_xor(t2, 1, 64);
                t2 += __shfl_xor(t2, 2, 64);
                t2 += __shfl_xor(t2, 4, 64);
                t2 += __shfl_xor(t2, 8, 64);
                float inv = rsqrtf(t2 * (1.f / 64.f) + 1e-5f);
                int m = m0 + wm * 64 + mi * 16 + kh * 4 + j;
                int b = m >> 12, ns = m & 4095;
                size_t base = ((((size_t)b * 16 + h) * 4096) + ns) * 64;
#pragma unroll
                for (int ni = 0; ni < 4; ni++) {
                    float y = (acc[mi][ni][j] - mu) * inv * gr[ni] + br[ni];
                    dst[base + ni * 16 + lrow] = f2bf(y);
                }
            }
    } else if (MODE == 1) {
#pragma unroll
        for (int mi = 0; mi < 4; mi++)
#pragma unroll
            for (int ni = 0; ni < 4; ni++) {
                int e = n0 + wn * 64 + ni * 16 + lrow;
                float bv2 = bias[e];
#pragma unroll
                for (int j = 0; j < 4; j++) {
                    int m = m0 + wm * 64 + mi * 16 + kh * 4 + j;
                    outf[(size_t)m * Nn + e] = acc[mi][ni][j] + bv2;
                }
            }
    } else {
        ushort* o = qo + (size_t)blockIdx.z * 1048576;
#pragma unroll
        for (int mi = 0; mi < 4; mi++)
#pragma unroll
            for (int ni = 0; ni < 4; ni++) {
                int e = n0 + wn * 64 + ni * 16 + lrow;
#pragma unroll
                for (int j = 0; j < 4; j++) {
                    int m = m0 + wm * 64 + mi * 16 + kh * 4 + j;
                    o[(size_t)m * 1024 + e] = f2bf(acc[mi][ni][j]);
                }
            }
    }
}

// ---------------- scores[bh][d][e] = sum_n kn[n,d]*vn[n,e] / 4096, fp32 atomics ----------------
__global__ __launch_bounds__(256) void scores_k(const ushort* __restrict__ kn,
                                                const ushort* __restrict__ vn,
                                                float* __restrict__ sc)
{
    __shared__ __align__(16) ushort ks[128][64];
    __shared__ __align__(16) ushort vs[128][64];
    int bh = blockIdx.y;
    int t = threadIdx.x;
    int d = t & 63, eg = t >> 6;
    const ushort* kb = kn + (size_t)bh * 4096 * 64;
    const ushort* vb = vn + (size_t)bh * 4096 * 64;
    float acc[16];
#pragma unroll
    for (int i = 0; i < 16; i++) acc[i] = 0.f;
    int c0 = blockIdx.x * 512;
    for (int cc = c0; cc < c0 + 512; cc += 128) {
        __syncthreads();
        for (int i = t; i < 1024; i += 256) {
            reinterpret_cast<int4*>(ks)[i] = *reinterpret_cast<const int4*>(kb + (size_t)cc * 64 + i * 8);
            reinterpret_cast<int4*>(vs)[i] = *reinterpret_cast<const int4*>(vb + (size_t)cc * 64 + i * 8);
        }
        __syncthreads();
        for (int n = 0; n < 128; ++n) {
            float kval = bf2f(ks[n][d]);
            uint4 v0 = *reinterpret_cast<const uint4*>(&vs[n][eg * 16]);
            uint4 v1 = *reinterpret_cast<const uint4*>(&vs[n][eg * 16 + 8]);
            unsigned vvv[8] = {v0.x, v0.y, v0.z, v0.w, v1.x, v1.y, v1.z, v1.w};
#pragma unroll
            for (int i = 0; i < 8; i++) {
                float lo = __uint_as_float(vvv[i] << 16);
                float hi = __uint_as_float(vvv[i] & 0xffff0000u);
                acc[2 * i]     = fmaf(kval, lo, acc[2 * i]);
                acc[2 * i + 1] = fmaf(kval, hi, acc[2 * i + 1]);
            }
        }
    }
    const float scale = 1.f / 4096.f;
#pragma unroll
    for (int i = 0; i < 16; i++)
        atomicAdd(&sc[(size_t)bh * 4096 + d * 64 + eg * 16 + i], acc[i] * scale);
}

// -------- W'T[b][f][h*64+d] = sum_e woutT[f][h*64+e] * sc[b*16+h][d][e], bf16 out --------
__global__ __launch_bounds__(256) void wprime_k(const float* __restrict__ sc,
                                                const ushort* __restrict__ woutT,
                                                ushort* __restrict__ wpT)
{
    __shared__ float scl[64][65];      // [e][d], padded
    __shared__ ushort wl[128][72];     // [f_local][e], padded
    int bh = blockIdx.y;
    int b = bh >> 4, h = bh & 15;
    int f0 = blockIdx.x * 128;
    int t = threadIdx.x;
    for (int i = t; i < 4096; i += 256) {
        int d2 = i >> 6, e = i & 63;
        scl[e][d2] = sc[(size_t)bh * 4096 + i];
    }
    for (int i = t; i < 1024; i += 256) {
        int fl = i >> 3, c = i & 7;
        *reinterpret_cast<int4*>(&wl[fl][c * 8]) =
            *reinterpret_cast<const int4*>(woutT + (size_t)(f0 + fl) * 1024 + h * 64 + c * 8);
    }
    __syncthreads();
    int dd = (t & 7) * 8;
    int fl0 = t >> 3;
#pragma unroll
    for (int fi = 0; fi < 4; ++fi) {
        int fl = fi * 32 + fl0;
        float acc[8] = {};
        for (int e = 0; e < 64; ++e) {
            float wv = bf2f(wl[fl][e]);
#pragma unroll
            for (int i = 0; i < 8; ++i)
                acc[i] = fmaf(wv, scl[e][dd + i], acc[i]);
        }
        ushort4 o0, o1;
        o0.x = f2bf(acc[0]); o0.y = f2bf(acc[1]); o0.z = f2bf(acc[2]); o0.w = f2bf(acc[3]);
        o1.x = f2bf(acc[4]); o1.y = f2bf(acc[5]); o1.z = f2bf(acc[6]); o1.w = f2bf(acc[7]);
        ushort* op = wpT + ((size_t)b * 1024 + f0 + fl) * 1024 + h * 64 + dd;
        *reinterpret_cast<ushort4*>(op) = o0;
        *reinterpret_cast<ushort4*>(op + 4) = o1;
    }
}

extern "C" void kernel_launch(void* const* d_in, const int* in_sizes, int n_in,
                              void* d_out, int out_size, void* d_ws, size_t ws_size,
                              hipStream_t stream)
{
    const float* x       = (const float*)d_in[0];
    const float* w_qkv   = (const float*)d_in[1];
    const float* gamma_k = (const float*)d_in[2];
    const float* beta_k  = (const float*)d_in[3];
    const float* gamma_v = (const float*)d_in[4];
    const float* beta_v  = (const float*)d_in[5];
    const float* w_out   = (const float*)d_in[6];
    const float* b_out   = (const float*)d_in[7];
    float* out = (float*)d_out;

    char* ws = (char*)d_ws;
    const size_t MB = 1024 * 1024;
    ushort* xb    = (ushort*)(ws);               // 32MB [m][1024] (alive through GEMM2)
    ushort* wkvT  = (ushort*)(ws + 32 * MB);     // 4MB  [2048][1024] (k,v cols of w_qkv, transposed)
    ushort* woutT = (ushort*)(ws + 38 * MB);     // 2MB  [1024][1024]
    ushort* wqb   = (ushort*)(ws + 40 * MB);     // 2MB  [c][1024] (q cols of w_qkv, row-major)
    ushort* kb    = (ushort*)(ws + 48 * MB);     // 32MB [b][h][n][64]
    ushort* vb    = (ushort*)(ws + 80 * MB);     // 32MB
    float*  sc    = (float*)(ws + 112 * MB);     // 1MB  [bh][d][e]
    ushort* wpT   = (ushort*)(ws + 120 * MB);    // 8MB  [b][f][h*64+d]
    ushort* fT    = (ushort*)(ws + 128 * MB);    // 8MB  [b][f][c]  (fused weight, transposed)

    pack_x_k<<<2048, 256, 0, stream>>>(x, xb, 16384 * 1024 / 4);
    pack_wq_k<<<1024, 256, 0, stream>>>(w_qkv, wqb);
    trans_pack_k<<<dim3(64, 32), dim3(32, 8), 0, stream>>>(w_qkv, wkvT, 1024, 3072, 1024);
    trans_pack_k<<<dim3(32, 32), dim3(32, 8), 0, stream>>>(w_out, woutT, 1024, 1024, 0);
    // GEMM1: k,v only + fused per-head LN + scatter
    gemm_bt_k<0><<<dim3(16, 128), 256, 0, stream>>>(xb, wkvT, 2048, 1024, 1024, 0, 0,
                                                    nullptr, kb, vb,
                                                    gamma_k, beta_k, gamma_v, beta_v,
                                                    nullptr, nullptr);
    hipMemsetAsync(sc, 0, 64 * 4096 * sizeof(float), stream);
    scores_k<<<dim3(8, 64), 256, 0, stream>>>(kb, vb, sc);
    wprime_k<<<dim3(8, 64), 256, 0, stream>>>(sc, woutT, wpT);
    // fold: fT[b][f][c] = sum_d wpT[b][f][d] * wqb[c][d]
    gemm_bt_k<2><<<dim3(8, 8, 4), 256, 0, stream>>>(wpT, wqb, 1024, 1024, 0, 0, (size_t)1048576,
                                                    fT, nullptr, nullptr,
                                                    nullptr, nullptr, nullptr, nullptr,
                                                    nullptr, nullptr);
    // GEMM2: out = xb · fT(b)^T + bias
    gemm_bt_k<1><<<dim3(8, 128), 256, 0, stream>>>(xb, fT, 1024, 1024, 0, (size_t)1048576, 0,
                                                   nullptr, nullptr, nullptr,
                                                   nullptr, nullptr, nullptr, nullptr,
                                                   b_out, out);
}

// Round 5
// 264.857 us; speedup vs baseline: 1.8144x; 1.4751x over previous
//
#include <hip/hip_runtime.h>

typedef __attribute__((ext_vector_type(4))) float f32x4;
typedef __attribute__((ext_vector_type(8))) short s16x8;

#define DEV static __device__ __forceinline__

typedef __attribute__((address_space(3))) void lds_t;
typedef __attribute__((address_space(1))) void gbl_t;

DEV void gload_lds16(const void* g, void* l) {
    __builtin_amdgcn_global_load_lds((gbl_t*)g, (lds_t*)l, 16, 0, 0);
}

DEV ushort f2bf(float f) {
    unsigned u = __float_as_uint(f);
    u += 0x7fffu + ((u >> 16) & 1u);   // round-to-nearest-even
    return (ushort)(u >> 16);
}
DEV float bf2f(ushort h) { return __uint_as_float(((unsigned)h) << 16); }

// ---------------- pack x (fp32 -> bf16) ----------------
__global__ void pack_x_k(const float* __restrict__ x, ushort* __restrict__ xb, int n4) {
    int stride = gridDim.x * blockDim.x;
    for (int i = blockIdx.x * blockDim.x + threadIdx.x; i < n4; i += stride) {
        float4 v = reinterpret_cast<const float4*>(x)[i];
        ushort4 o;
        o.x = f2bf(v.x); o.y = f2bf(v.y); o.z = f2bf(v.z); o.w = f2bf(v.w);
        reinterpret_cast<ushort4*>(xb)[i] = o;
    }
}

// ---- pack Wq slice (no transpose): wqb[c][d'] = bf16(w_qkv[c][d']), d'<1024, row stride 3072 ----
__global__ void pack_wq_k(const float* __restrict__ w, ushort* __restrict__ o) {
    int i = blockIdx.x * 256 + threadIdx.x;   // over 1024*256 float4 groups
    int r = i >> 8, c4 = i & 255;
    float4 v = *reinterpret_cast<const float4*>(w + (size_t)r * 3072 + c4 * 4);
    ushort4 u;
    u.x = f2bf(v.x); u.y = f2bf(v.y); u.z = f2bf(v.z); u.w = f2bf(v.w);
    *reinterpret_cast<ushort4*>(o + (size_t)r * 1024 + c4 * 4) = u;
}

// ------- transpose + pack: in fp32 [R][C], cols col0.., -> out bf16 [C-col0][R] -------
__global__ void trans_pack_k(const float* __restrict__ in, ushort* __restrict__ out,
                             int R, int C, int col0) {
    __shared__ float tile[32][33];
    int bx = col0 + blockIdx.x * 32, by = blockIdx.y * 32;
    int tx = threadIdx.x, ty = threadIdx.y;
#pragma unroll
    for (int i = 0; i < 32; i += 8)
        tile[ty + i][tx] = in[(size_t)(by + ty + i) * C + bx + tx];
    __syncthreads();
#pragma unroll
    for (int i = 0; i < 32; i += 8)
        out[(size_t)(bx - col0 + ty + i) * R + by + tx] = f2bf(tile[tx][ty + i]);
}

// ---------------- main GEMM: C[M][Nn] = A[M][K](bf16) * Bt[Nn][K]^T (bf16), fp32 acc ----------------
// global_load_lds width-16 staging, linear LDS [128][32] (m97 structure), XCD-chunked swizzle.
// MODE 0: per-head LayerNorm fused on every 64-col group; TRANSPOSED scatter to
//         kT/vT [b][h][d][n] bf16 via in-LDS per-wave transpose.
// MODE 1: add bias, write fp32 to outf[M][Nn]; Bt selected per-b via b_stride (b = m0>>12).
// MODE 2: bf16 out to qo (per-b via blockIdx.z: A += z*a_bstride, qo += z*2^20), no swizzle.
template <int MODE>
__global__ __launch_bounds__(256) void gemm_bt_k(
    const ushort* __restrict__ A, const ushort* __restrict__ Bt,
    int Nn, int K, int col0, size_t b_stride, size_t a_bstride,
    ushort* __restrict__ qo, ushort* __restrict__ ko, ushort* __restrict__ vo,
    const float* __restrict__ gk, const float* __restrict__ bk,
    const float* __restrict__ gv, const float* __restrict__ bv,
    const float* __restrict__ bias, float* __restrict__ outf)
{
    // MODE 0 needs 4 waves * 64 * 72 ushorts for the transpose buffer (unioned over Al/Bl)
    __shared__ __align__(16) ushort SH[(MODE == 0) ? 18432 : 8192];
    ushort* Al = SH;
    ushort* Bl = SH + 4096;
    const int t = threadIdx.x;
    const int w = t >> 6, lane = t & 63;
    const int wm = w >> 1, wn = w & 1;
    const int lrow = lane & 15, kh = lane >> 4;

    int n0, m0;
    if (MODE == 2) {
        n0 = blockIdx.x * 128; m0 = blockIdx.y * 128;
    } else {
        // bijective XCD-chunked swizzle (grid total % 8 == 0)
        int bid = blockIdx.y * gridDim.x + blockIdx.x;
        int C8 = (gridDim.x * gridDim.y) >> 3;
        int nid = (bid & 7) * C8 + (bid >> 3);
        n0 = (nid % gridDim.x) * 128;
        m0 = (nid / gridDim.x) * 128;
    }

    const ushort* Ae  = (MODE == 2) ? A + blockIdx.z * a_bstride : A;
    const ushort* Bte = (MODE == 1) ? Bt + (size_t)(m0 >> 12) * b_stride : Bt;

    const int srow0 = w * 32 + (lane >> 2);
    const int scol = (lane & 3) * 8;

    f32x4 acc[4][4] = {};

    for (int k0 = 0; k0 < K; k0 += 32) {
        __syncthreads();
        gload_lds16(Ae  + (size_t)(m0 + srow0)      * K + k0 + scol, Al + w * 1024);
        gload_lds16(Bte + (size_t)(n0 + srow0)      * K + k0 + scol, Bl + w * 1024);
        gload_lds16(Ae  + (size_t)(m0 + srow0 + 16) * K + k0 + scol, Al + w * 1024 + 512);
        gload_lds16(Bte + (size_t)(n0 + srow0 + 16) * K + k0 + scol, Bl + w * 1024 + 512);
        __syncthreads();
        s16x8 af[4], bfr[4];
#pragma unroll
        for (int mi = 0; mi < 4; mi++)
            af[mi] = *reinterpret_cast<const s16x8*>(&Al[(wm * 64 + mi * 16 + lrow) * 32 + kh * 8]);
#pragma unroll
        for (int ni = 0; ni < 4; ni++)
            bfr[ni] = *reinterpret_cast<const s16x8*>(&Bl[(wn * 64 + ni * 16 + lrow) * 32 + kh * 8]);
#pragma unroll
        for (int mi = 0; mi < 4; mi++)
#pragma unroll
            for (int ni = 0; ni < 4; ni++)
                acc[mi][ni] = __builtin_amdgcn_mfma_f32_16x16x32_bf16(af[mi], bfr[ni], acc[mi][ni], 0, 0, 0);
    }

    // C/D layout (verified m89): col = lane&15, row = (lane>>4)*4 + reg
    if (MODE == 0) {
        const int e0 = col0 + n0 + wn * 64;   // aligned 64-col group == one head
        const int which = e0 >> 10;           // 1=k, 2=v
        const int h = (e0 >> 6) & 15;
        const float* g  = (which == 1) ? gk : gv;
        const float* bb = (which == 1) ? bk : bv;
        ushort* dst     = (which == 1) ? ko : vo;
        float gr[4], br[4];
#pragma unroll
        for (int ni = 0; ni < 4; ni++) {
            gr[ni] = g[h * 64 + ni * 16 + lrow];
            br[ni] = bb[h * 64 + ni * 16 + lrow];
        }
        __syncthreads();                       // Al/Bl dead for ALL waves; Tl overlays them
        ushort* Tl = SH + w * 4608;            // this wave's [64 d][72 pitch] transpose tile
#pragma unroll
        for (int mi = 0; mi < 4; mi++)
#pragma unroll
            for (int j = 0; j < 4; j++) {
                float s = acc[mi][0][j] + acc[mi][1][j] + acc[mi][2][j] + acc[mi][3][j];
                s += __shfl_xor(s, 1, 64);
                s += __shfl_xor(s, 2, 64);
                s += __shfl_xor(s, 4, 64);
                s += __shfl_xor(s, 8, 64);
                float mu = s * (1.f / 64.f);
                float t2 = 0.f;
#pragma unroll
                for (int ni = 0; ni < 4; ni++) {
                    float dd = acc[mi][ni][j] - mu;
                    t2 += dd * dd;
                }
                t2 += __shfl_xor(t2, 1, 64);
                t2 += __shfl_xor(t2, 2, 64);
                t2 += __shfl_xor(t2, 4, 64);
                t2 += __shfl_xor(t2, 8, 64);
                float inv = rsqrtf(t2 * (1.f / 64.f) + 1e-5f);
#pragma unroll
                for (int ni = 0; ni < 4; ni++) {
                    float y = (acc[mi][ni][j] - mu) * inv * gr[ni] + br[ni];
                    Tl[(ni * 16 + lrow) * 72 + mi * 16 + kh * 4 + j] = f2bf(y);
                }
            }
        // write out transposed: kT[b][h][d][n], coalesced 128B row chunks
        const int mrow0 = m0 + wm * 64;
        const int b = mrow0 >> 12, ns0 = mrow0 & 4095;
        ushort* obase = dst + (((size_t)b * 16 + h) * 64) * 4096 + ns0;
#pragma unroll
        for (int p = 0; p < 8; ++p) {
            int d = p * 8 + (lane >> 3);
            int mo = (lane & 7) * 8;
            s16x8 vv = *reinterpret_cast<const s16x8*>(&Tl[d * 72 + mo]);
            *reinterpret_cast<s16x8*>(obase + (size_t)d * 4096 + mo) = vv;
        }
    } else if (MODE == 1) {
#pragma unroll
        for (int mi = 0; mi < 4; mi++)
#pragma unroll
            for (int ni = 0; ni < 4; ni++) {
                int e = n0 + wn * 64 + ni * 16 + lrow;
                float bv2 = bias[e];
#pragma unroll
                for (int j = 0; j < 4; j++) {
                    int m = m0 + wm * 64 + mi * 16 + kh * 4 + j;
                    outf[(size_t)m * Nn + e] = acc[mi][ni][j] + bv2;
                }
            }
    } else {
        ushort* o = qo + (size_t)blockIdx.z * 1048576;
#pragma unroll
        for (int mi = 0; mi < 4; mi++)
#pragma unroll
            for (int ni = 0; ni < 4; ni++) {
                int e = n0 + wn * 64 + ni * 16 + lrow;
#pragma unroll
                for (int j = 0; j < 4; j++) {
                    int m = m0 + wm * 64 + mi * 16 + kh * 4 + j;
                    o[(size_t)m * 1024 + e] = f2bf(acc[mi][ni][j]);
                }
            }
    }
}

// ---- scores[bh][d][e] = sum_n kT[bh][d][n]*vT[bh][e][n] / 4096, MFMA, fp32 atomics ----
// kT/vT: [b][h][d=64][n=4096] bf16. grid (8, 64); wave reduces 128 n (4 K-steps).
__global__ __launch_bounds__(256) void scores_k(const ushort* __restrict__ kT,
                                                const ushort* __restrict__ vT,
                                                float* __restrict__ sc)
{
    __shared__ float red[4][64][65];
    const int bh = blockIdx.y;
    const int t = threadIdx.x;
    const int w = t >> 6, lane = t & 63;
    const int lrow = lane & 15, kh = lane >> 4;
    const ushort* ka = kT + (size_t)bh * 64 * 4096;
    const ushort* va = vT + (size_t)bh * 64 * 4096;
    const int n0 = blockIdx.x * 512 + w * 128;

    f32x4 acc[4][4] = {};
#pragma unroll
    for (int ks = 0; ks < 4; ++ks) {
        const int n = n0 + ks * 32 + kh * 8;
        s16x8 af[4], bfr[4];
#pragma unroll
        for (int mi = 0; mi < 4; mi++)
            af[mi] = *reinterpret_cast<const s16x8*>(ka + (size_t)(mi * 16 + lrow) * 4096 + n);
#pragma unroll
        for (int ni = 0; ni < 4; ni++)
            bfr[ni] = *reinterpret_cast<const s16x8*>(va + (size_t)(ni * 16 + lrow) * 4096 + n);
#pragma unroll
        for (int mi = 0; mi < 4; mi++)
#pragma unroll
            for (int ni = 0; ni < 4; ni++)
                acc[mi][ni] = __builtin_amdgcn_mfma_f32_16x16x32_bf16(af[mi], bfr[ni], acc[mi][ni], 0, 0, 0);
    }
    // C layout: row d = mi*16+kh*4+j, col e = ni*16+lrow
#pragma unroll
    for (int mi = 0; mi < 4; mi++)
#pragma unroll
        for (int ni = 0; ni < 4; ni++)
#pragma unroll
            for (int j = 0; j < 4; j++)
                red[w][mi * 16 + kh * 4 + j][ni * 16 + lrow] = acc[mi][ni][j];
    __syncthreads();
    const float scale = 1.f / 4096.f;
    for (int idx = t; idx < 4096; idx += 256) {
        int d = idx >> 6, e = idx & 63;
        float s = red[0][d][e] + red[1][d][e] + red[2][d][e] + red[3][d][e];
        atomicAdd(&sc[(size_t)bh * 4096 + idx], s * scale);
    }
}

// -------- W'T[b][f][h*64+d] = sum_e woutT[f][h*64+e] * sc[b*16+h][d][e], bf16 out --------
__global__ __launch_bounds__(256) void wprime_k(const float* __restrict__ sc,
                                                const ushort* __restrict__ woutT,
                                                ushort* __restrict__ wpT)
{
    __shared__ float scl[64][65];      // [e][d], padded
    __shared__ ushort wl[128][72];     // [f_local][e], padded
    int bh = blockIdx.y;
    int b = bh >> 4, h = bh & 15;
    int f0 = blockIdx.x * 128;
    int t = threadIdx.x;
    for (int i = t; i < 4096; i += 256) {
        int d2 = i >> 6, e = i & 63;
        scl[e][d2] = sc[(size_t)bh * 4096 + i];
    }
    for (int i = t; i < 1024; i += 256) {
        int fl = i >> 3, c = i & 7;
        *reinterpret_cast<int4*>(&wl[fl][c * 8]) =
            *reinterpret_cast<const int4*>(woutT + (size_t)(f0 + fl) * 1024 + h * 64 + c * 8);
    }
    __syncthreads();
    int dd = (t & 7) * 8;
    int fl0 = t >> 3;
#pragma unroll
    for (int fi = 0; fi < 4; ++fi) {
        int fl = fi * 32 + fl0;
        float acc[8] = {};
        for (int e = 0; e < 64; ++e) {
            float wv = bf2f(wl[fl][e]);
#pragma unroll
            for (int i = 0; i < 8; ++i)
                acc[i] = fmaf(wv, scl[e][dd + i], acc[i]);
        }
        ushort4 o0, o1;
        o0.x = f2bf(acc[0]); o0.y = f2bf(acc[1]); o0.z = f2bf(acc[2]); o0.w = f2bf(acc[3]);
        o1.x = f2bf(acc[4]); o1.y = f2bf(acc[5]); o1.z = f2bf(acc[6]); o1.w = f2bf(acc[7]);
        ushort* op = wpT + ((size_t)b * 1024 + f0 + fl) * 1024 + h * 64 + dd;
        *reinterpret_cast<ushort4*>(op) = o0;
        *reinterpret_cast<ushort4*>(op + 4) = o1;
    }
}

extern "C" void kernel_launch(void* const* d_in, const int* in_sizes, int n_in,
                              void* d_out, int out_size, void* d_ws, size_t ws_size,
                              hipStream_t stream)
{
    const float* x       = (const float*)d_in[0];
    const float* w_qkv   = (const float*)d_in[1];
    const float* gamma_k = (const float*)d_in[2];
    const float* beta_k  = (const float*)d_in[3];
    const float* gamma_v = (const float*)d_in[4];
    const float* beta_v  = (const float*)d_in[5];
    const float* w_out   = (const float*)d_in[6];
    const float* b_out   = (const float*)d_in[7];
    float* out = (float*)d_out;

    char* ws = (char*)d_ws;
    const size_t MB = 1024 * 1024;
    ushort* xb    = (ushort*)(ws);               // 32MB [m][1024] (alive through GEMM2)
    ushort* wkvT  = (ushort*)(ws + 32 * MB);     // 4MB  [2048][1024] (k,v cols of w_qkv, transposed)
    ushort* woutT = (ushort*)(ws + 38 * MB);     // 2MB  [1024][1024]
    ushort* wqb   = (ushort*)(ws + 40 * MB);     // 2MB  [c][1024] (q cols of w_qkv, row-major)
    ushort* kb    = (ushort*)(ws + 48 * MB);     // 32MB [b][h][d][n]  (kT)
    ushort* vb    = (ushort*)(ws + 80 * MB);     // 32MB [b][h][d][n]  (vT)
    float*  sc    = (float*)(ws + 112 * MB);     // 1MB  [bh][d][e]
    ushort* wpT   = (ushort*)(ws + 120 * MB);    // 8MB  [b][f][h*64+d]
    ushort* fT    = (ushort*)(ws + 128 * MB);    // 8MB  [b][f][c]  (fused weight, transposed)

    pack_x_k<<<2048, 256, 0, stream>>>(x, xb, 16384 * 1024 / 4);
    pack_wq_k<<<1024, 256, 0, stream>>>(w_qkv, wqb);
    trans_pack_k<<<dim3(64, 32), dim3(32, 8), 0, stream>>>(w_qkv, wkvT, 1024, 3072, 1024);
    trans_pack_k<<<dim3(32, 32), dim3(32, 8), 0, stream>>>(w_out, woutT, 1024, 1024, 0);
    // GEMM1: k,v only + fused per-head LN + transposed scatter
    gemm_bt_k<0><<<dim3(16, 128), 256, 0, stream>>>(xb, wkvT, 2048, 1024, 1024, 0, 0,
                                                    nullptr, kb, vb,
                                                    gamma_k, beta_k, gamma_v, beta_v,
                                                    nullptr, nullptr);
    hipMemsetAsync(sc, 0, 64 * 4096 * sizeof(float), stream);
    scores_k<<<dim3(8, 64), 256, 0, stream>>>(kb, vb, sc);
    wprime_k<<<dim3(8, 64), 256, 0, stream>>>(sc, woutT, wpT);
    // fold: fT[b][f][c] = sum_d wpT[b][f][d] * wqb[c][d]
    gemm_bt_k<2><<<dim3(8, 8, 4), 256, 0, stream>>>(wpT, wqb, 1024, 1024, 0, 0, (size_t)1048576,
                                                    fT, nullptr, nullptr,
                                                    nullptr, nullptr, nullptr, nullptr,
                                                    nullptr, nullptr);
    // GEMM2: out = xb · fT(b)^T + bias
    gemm_bt_k<1><<<dim3(8, 128), 256, 0, stream>>>(xb, fT, 1024, 1024, 0, (size_t)1048576, 0,
                                                   nullptr, nullptr, nullptr,
                                                   nullptr, nullptr, nullptr, nullptr,
                                                   b_out, out);
}

// Round 6
// 236.685 us; speedup vs baseline: 2.0304x; 1.1190x over previous
//
#include <hip/hip_runtime.h>

typedef __attribute__((ext_vector_type(4))) float f32x4;
typedef __attribute__((ext_vector_type(8))) short s16x8;

#define DEV static __device__ __forceinline__

typedef __attribute__((address_space(3))) void lds_t;
typedef __attribute__((address_space(1))) void gbl_t;

DEV void gload_lds16(const void* g, void* l) {
    __builtin_amdgcn_global_load_lds((gbl_t*)g, (lds_t*)l, 16, 0, 0);
}

DEV ushort f2bf(float f) {
    unsigned u = __float_as_uint(f);
    u += 0x7fffu + ((u >> 16) & 1u);   // round-to-nearest-even
    return (ushort)(u >> 16);
}
DEV float bf2f(ushort h) { return __uint_as_float(((unsigned)h) << 16); }

// raw barrier with compiler+scheduler fences (no vmcnt(0) drain, unlike __syncthreads)
#define FULLBAR() do {                              \
    __builtin_amdgcn_sched_barrier(0);              \
    asm volatile("" ::: "memory");                  \
    __builtin_amdgcn_s_barrier();                   \
    asm volatile("" ::: "memory");                  \
    __builtin_amdgcn_sched_barrier(0);              \
} while (0)

#define WAITVM(n) asm volatile("s_waitcnt vmcnt(" #n ")" ::: "memory")

// ---------------- pack x (fp32 -> bf16) ----------------
__global__ void pack_x_k(const float* __restrict__ x, ushort* __restrict__ xb, int n4) {
    int stride = gridDim.x * blockDim.x;
    for (int i = blockIdx.x * blockDim.x + threadIdx.x; i < n4; i += stride) {
        float4 v = reinterpret_cast<const float4*>(x)[i];
        ushort4 o;
        o.x = f2bf(v.x); o.y = f2bf(v.y); o.z = f2bf(v.z); o.w = f2bf(v.w);
        reinterpret_cast<ushort4*>(xb)[i] = o;
    }
}

// ---- pack Wq slice (no transpose): wqb[c][d'] = bf16(w_qkv[c][d']), d'<1024, row stride 3072 ----
__global__ void pack_wq_k(const float* __restrict__ w, ushort* __restrict__ o) {
    int i = blockIdx.x * 256 + threadIdx.x;   // over 1024*256 float4 groups
    int r = i >> 8, c4 = i & 255;
    float4 v = *reinterpret_cast<const float4*>(w + (size_t)r * 3072 + c4 * 4);
    ushort4 u;
    u.x = f2bf(v.x); u.y = f2bf(v.y); u.z = f2bf(v.z); u.w = f2bf(v.w);
    *reinterpret_cast<ushort4*>(o + (size_t)r * 1024 + c4 * 4) = u;
}

// ------- transpose + pack: in fp32 [R][C], cols col0.., -> out bf16 [C-col0][R] -------
__global__ void trans_pack_k(const float* __restrict__ in, ushort* __restrict__ out,
                             int R, int C, int col0) {
    __shared__ float tile[32][33];
    int bx = col0 + blockIdx.x * 32, by = blockIdx.y * 32;
    int tx = threadIdx.x, ty = threadIdx.y;
#pragma unroll
    for (int i = 0; i < 32; i += 8)
        tile[ty + i][tx] = in[(size_t)(by + ty + i) * C + bx + tx];
    __syncthreads();
#pragma unroll
    for (int i = 0; i < 32; i += 8)
        out[(size_t)(bx - col0 + ty + i) * R + by + tx] = f2bf(tile[tx][ty + i]);
}

// ---------------- main GEMM: C[M][Nn] = A[M][K=1024](bf16) * Bt[Nn][1024]^T (bf16), fp32 acc --------
// 128x128 tile, BK=32, 3-slot LDS ring, 2-K-tile-deep global_load_lds prefetch, counted vmcnt(8),
// raw s_barrier (no vmcnt(0) drain in main loop). XCD-chunked swizzle (MODE 0/1).
// MODE 0: per-head LayerNorm fused; TRANSPOSED scatter to kT/vT [b][h][d][n] via in-LDS transpose.
// MODE 1: add bias, write fp32 to outf[M][Nn]; Bt selected per-b via b_stride (b = m0>>12).
// MODE 2: bf16 out to qo (per-b via blockIdx.z: A += z*a_bstride, qo += z*2^20), no swizzle.
template <int MODE>
__global__ __launch_bounds__(256) void gemm_bt_k(
    const ushort* __restrict__ A, const ushort* __restrict__ Bt,
    int Nn, int col0, size_t b_stride, size_t a_bstride,
    ushort* __restrict__ qo, ushort* __restrict__ ko, ushort* __restrict__ vo,
    const float* __restrict__ gk, const float* __restrict__ bk,
    const float* __restrict__ gv, const float* __restrict__ bv,
    const float* __restrict__ bias, float* __restrict__ outf)
{
    // 3 ring slots x (A 4096 + B 4096) ushorts = 48 KB. MODE-0 transpose buffer overlays (36 KB).
    __shared__ __align__(16) ushort SH[24576];
    const int t = threadIdx.x;
    const int w = t >> 6, lane = t & 63;
    const int wm = w >> 1, wn = w & 1;
    const int lrow = lane & 15, kh = lane >> 4;

    int n0, m0;
    if (MODE == 2) {
        n0 = blockIdx.x * 128; m0 = blockIdx.y * 128;
    } else {
        // bijective XCD-chunked swizzle (grid total % 8 == 0)
        int bid = blockIdx.y * gridDim.x + blockIdx.x;
        int C8 = (gridDim.x * gridDim.y) >> 3;
        int nid = (bid & 7) * C8 + (bid >> 3);
        n0 = (nid % gridDim.x) * 128;
        m0 = (nid / gridDim.x) * 128;
    }

    const ushort* Ae  = (MODE == 2) ? A + blockIdx.z * a_bstride : A;
    const ushort* Bte = (MODE == 1) ? Bt + (size_t)(m0 >> 12) * b_stride : Bt;

    const int srow0 = w * 32 + (lane >> 2);   // staging row (call 0); call 1 = +16
    const int scol = (lane & 3) * 8;          // staging k-offset (elems)

    f32x4 acc[4][4] = {};

    // stage K-tile kt into ring slot s (4 x global_load_lds_dwordx4 per thread)
    auto STAGE = [&](int kt, int s) {
        ushort* As = SH + s * 8192;
        ushort* Bs = As + 4096;
        const ushort* Ag = Ae  + (size_t)(m0 + srow0) * 1024 + kt * 32 + scol;
        const ushort* Bg = Bte + (size_t)(n0 + srow0) * 1024 + kt * 32 + scol;
        gload_lds16(Ag,             As + w * 1024);
        gload_lds16(Bg,             Bs + w * 1024);
        gload_lds16(Ag + 16 * 1024, As + w * 1024 + 512);
        gload_lds16(Bg + 16 * 1024, Bs + w * 1024 + 512);
    };

    auto COMPUTE = [&](int s) {
        const ushort* As = SH + s * 8192;
        const ushort* Bs = As + 4096;
        s16x8 af[4], bfr[4];
#pragma unroll
        for (int mi = 0; mi < 4; mi++)
            af[mi] = *reinterpret_cast<const s16x8*>(&As[(wm * 64 + mi * 16 + lrow) * 32 + kh * 8]);
#pragma unroll
        for (int ni = 0; ni < 4; ni++)
            bfr[ni] = *reinterpret_cast<const s16x8*>(&Bs[(wn * 64 + ni * 16 + lrow) * 32 + kh * 8]);
#pragma unroll
        for (int mi = 0; mi < 4; mi++)
#pragma unroll
            for (int ni = 0; ni < 4; ni++)
                acc[mi][ni] = __builtin_amdgcn_mfma_f32_16x16x32_bf16(af[mi], bfr[ni], acc[mi][ni], 0, 0, 0);
    };

    // prologue: 2 K-tiles in flight
    STAGE(0, 0);
    STAGE(1, 1);
    int ss = 2, sc_ = 0;    // stage slot for kt+2, compute slot for kt
    for (int kt = 0; kt < 30; ++kt) {
        STAGE(kt + 2, ss);
        ss = (ss == 2) ? 0 : ss + 1;
        WAITVM(8);          // stage(kt) landed; stage(kt+1), stage(kt+2) still in flight
        FULLBAR();
        COMPUTE(sc_);
        sc_ = (sc_ == 2) ? 0 : sc_ + 1;
        FULLBAR();
    }
    // tail: kt=30 (slot 0), kt=31 (slot 1)
    WAITVM(4); FULLBAR(); COMPUTE(0); FULLBAR();
    WAITVM(0); FULLBAR(); COMPUTE(1);

    // C/D layout (verified m89): col = lane&15, row = (lane>>4)*4 + reg
    if (MODE == 0) {
        const int e0 = col0 + n0 + wn * 64;   // aligned 64-col group == one head
        const int which = e0 >> 10;           // 1=k, 2=v
        const int h = (e0 >> 6) & 15;
        const float* g  = (which == 1) ? gk : gv;
        const float* bb = (which == 1) ? bk : bv;
        ushort* dst     = (which == 1) ? ko : vo;
        float gr[4], br[4];
#pragma unroll
        for (int ni = 0; ni < 4; ni++) {
            gr[ni] = g[h * 64 + ni * 16 + lrow];
            br[ni] = bb[h * 64 + ni * 16 + lrow];
        }
        __syncthreads();                       // staging LDS dead for ALL waves; Tl overlays
        ushort* Tl = SH + w * 4608;            // this wave's [64 d][72 pitch] transpose tile
#pragma unroll
        for (int mi = 0; mi < 4; mi++)
#pragma unroll
            for (int j = 0; j < 4; j++) {
                float s = acc[mi][0][j] + acc[mi][1][j] + acc[mi][2][j] + acc[mi][3][j];
                s += __shfl_xor(s, 1, 64);
                s += __shfl_xor(s, 2, 64);
                s += __shfl_xor(s, 4, 64);
                s += __shfl_xor(s, 8, 64);
                float mu = s * (1.f / 64.f);
                float t2 = 0.f;
#pragma unroll
                for (int ni = 0; ni < 4; ni++) {
                    float dd = acc[mi][ni][j] - mu;
                    t2 += dd * dd;
                }
                t2 += __shfl_xor(t2, 1, 64);
                t2 += __shfl_xor(t2, 2, 64);
                t2 += __shfl_xor(t2, 4, 64);
                t2 += __shfl_xor(t2, 8, 64);
                float inv = rsqrtf(t2 * (1.f / 64.f) + 1e-5f);
#pragma unroll
                for (int ni = 0; ni < 4; ni++) {
                    float y = (acc[mi][ni][j] - mu) * inv * gr[ni] + br[ni];
                    Tl[(ni * 16 + lrow) * 72 + mi * 16 + kh * 4 + j] = f2bf(y);
                }
            }
        // write out transposed: kT[b][h][d][n], coalesced 128B row chunks
        const int mrow0 = m0 + wm * 64;
        const int b = mrow0 >> 12, ns0 = mrow0 & 4095;
        ushort* obase = dst + (((size_t)b * 16 + h) * 64) * 4096 + ns0;
#pragma unroll
        for (int p = 0; p < 8; ++p) {
            int d = p * 8 + (lane >> 3);
            int mo = (lane & 7) * 8;
            s16x8 vv = *reinterpret_cast<const s16x8*>(&Tl[d * 72 + mo]);
            *reinterpret_cast<s16x8*>(obase + (size_t)d * 4096 + mo) = vv;
        }
    } else if (MODE == 1) {
#pragma unroll
        for (int mi = 0; mi < 4; mi++)
#pragma unroll
            for (int ni = 0; ni < 4; ni++) {
                int e = n0 + wn * 64 + ni * 16 + lrow;
                float bv2 = bias[e];
#pragma unroll
                for (int j = 0; j < 4; j++) {
                    int m = m0 + wm * 64 + mi * 16 + kh * 4 + j;
                    outf[(size_t)m * Nn + e] = acc[mi][ni][j] + bv2;
                }
            }
    } else {
        ushort* o = qo + (size_t)blockIdx.z * 1048576;
#pragma unroll
        for (int mi = 0; mi < 4; mi++)
#pragma unroll
            for (int ni = 0; ni < 4; ni++) {
                int e = n0 + wn * 64 + ni * 16 + lrow;
#pragma unroll
                for (int j = 0; j < 4; j++) {
                    int m = m0 + wm * 64 + mi * 16 + kh * 4 + j;
                    o[(size_t)m * 1024 + e] = f2bf(acc[mi][ni][j]);
                }
            }
    }
}

// ---- scores[bh][d][e] = sum_n kT[bh][d][n]*vT[bh][e][n] / 4096, MFMA, fp32 atomics ----
// kT/vT: [b][h][d=64][n=4096] bf16. grid (8, 64); wave reduces 128 n (4 K-steps).
__global__ __launch_bounds__(256) void scores_k(const ushort* __restrict__ kT,
                                                const ushort* __restrict__ vT,
                                                float* __restrict__ sc)
{
    __shared__ float red[4][64][65];
    const int bh = blockIdx.y;
    const int t = threadIdx.x;
    const int w = t >> 6, lane = t & 63;
    const int lrow = lane & 15, kh = lane >> 4;
    const ushort* ka = kT + (size_t)bh * 64 * 4096;
    const ushort* va = vT + (size_t)bh * 64 * 4096;
    const int n0 = blockIdx.x * 512 + w * 128;

    f32x4 acc[4][4] = {};
#pragma unroll
    for (int ks = 0; ks < 4; ++ks) {
        const int n = n0 + ks * 32 + kh * 8;
        s16x8 af[4], bfr[4];
#pragma unroll
        for (int mi = 0; mi < 4; mi++)
            af[mi] = *reinterpret_cast<const s16x8*>(ka + (size_t)(mi * 16 + lrow) * 4096 + n);
#pragma unroll
        for (int ni = 0; ni < 4; ni++)
            bfr[ni] = *reinterpret_cast<const s16x8*>(va + (size_t)(ni * 16 + lrow) * 4096 + n);
#pragma unroll
        for (int mi = 0; mi < 4; mi++)
#pragma unroll
            for (int ni = 0; ni < 4; ni++)
                acc[mi][ni] = __builtin_amdgcn_mfma_f32_16x16x32_bf16(af[mi], bfr[ni], acc[mi][ni], 0, 0, 0);
    }
    // C layout: row d = mi*16+kh*4+j, col e = ni*16+lrow
#pragma unroll
    for (int mi = 0; mi < 4; mi++)
#pragma unroll
        for (int ni = 0; ni < 4; ni++)
#pragma unroll
            for (int j = 0; j < 4; j++)
                red[w][mi * 16 + kh * 4 + j][ni * 16 + lrow] = acc[mi][ni][j];
    __syncthreads();
    const float scale = 1.f / 4096.f;
    for (int idx = t; idx < 4096; idx += 256) {
        int d = idx >> 6, e = idx & 63;
        float s = red[0][d][e] + red[1][d][e] + red[2][d][e] + red[3][d][e];
        atomicAdd(&sc[(size_t)bh * 4096 + idx], s * scale);
    }
}

// -------- W'T[b][f][h*64+d] = sum_e woutT[f][h*64+e] * sc[b*16+h][d][e], bf16 out --------
__global__ __launch_bounds__(256) void wprime_k(const float* __restrict__ sc,
                                                const ushort* __restrict__ woutT,
                                                ushort* __restrict__ wpT)
{
    __shared__ float scl[64][65];      // [e][d], padded
    __shared__ ushort wl[128][72];     // [f_local][e], padded
    int bh = blockIdx.y;
    int b = bh >> 4, h = bh & 15;
    int f0 = blockIdx.x * 128;
    int t = threadIdx.x;
    for (int i = t; i < 4096; i += 256) {
        int d2 = i >> 6, e = i & 63;
        scl[e][d2] = sc[(size_t)bh * 4096 + i];
    }
    for (int i = t; i < 1024; i += 256) {
        int fl = i >> 3, c = i & 7;
        *reinterpret_cast<int4*>(&wl[fl][c * 8]) =
            *reinterpret_cast<const int4*>(woutT + (size_t)(f0 + fl) * 1024 + h * 64 + c * 8);
    }
    __syncthreads();
    int dd = (t & 7) * 8;
    int fl0 = t >> 3;
#pragma unroll
    for (int fi = 0; fi < 4; ++fi) {
        int fl = fi * 32 + fl0;
        float acc[8] = {};
        for (int e = 0; e < 64; ++e) {
            float wv = bf2f(wl[fl][e]);
#pragma unroll
            for (int i = 0; i < 8; ++i)
                acc[i] = fmaf(wv, scl[e][dd + i], acc[i]);
        }
        ushort4 o0, o1;
        o0.x = f2bf(acc[0]); o0.y = f2bf(acc[1]); o0.z = f2bf(acc[2]); o0.w = f2bf(acc[3]);
        o1.x = f2bf(acc[4]); o1.y = f2bf(acc[5]); o1.z = f2bf(acc[6]); o1.w = f2bf(acc[7]);
        ushort* op = wpT + ((size_t)b * 1024 + f0 + fl) * 1024 + h * 64 + dd;
        *reinterpret_cast<ushort4*>(op) = o0;
        *reinterpret_cast<ushort4*>(op + 4) = o1;
    }
}

extern "C" void kernel_launch(void* const* d_in, const int* in_sizes, int n_in,
                              void* d_out, int out_size, void* d_ws, size_t ws_size,
                              hipStream_t stream)
{
    const float* x       = (const float*)d_in[0];
    const float* w_qkv   = (const float*)d_in[1];
    const float* gamma_k = (const float*)d_in[2];
    const float* beta_k  = (const float*)d_in[3];
    const float* gamma_v = (const float*)d_in[4];
    const float* beta_v  = (const float*)d_in[5];
    const float* w_out   = (const float*)d_in[6];
    const float* b_out   = (const float*)d_in[7];
    float* out = (float*)d_out;

    char* ws = (char*)d_ws;
    const size_t MB = 1024 * 1024;
    ushort* xb    = (ushort*)(ws);               // 32MB [m][1024] (alive through GEMM2)
    ushort* wkvT  = (ushort*)(ws + 32 * MB);     // 4MB  [2048][1024] (k,v cols of w_qkv, transposed)
    ushort* woutT = (ushort*)(ws + 38 * MB);     // 2MB  [1024][1024]
    ushort* wqb   = (ushort*)(ws + 40 * MB);     // 2MB  [c][1024] (q cols of w_qkv, row-major)
    ushort* kb    = (ushort*)(ws + 48 * MB);     // 32MB [b][h][d][n]  (kT)
    ushort* vb    = (ushort*)(ws + 80 * MB);     // 32MB [b][h][d][n]  (vT)
    float*  sc    = (float*)(ws + 112 * MB);     // 1MB  [bh][d][e]
    ushort* wpT   = (ushort*)(ws + 120 * MB);    // 8MB  [b][f][h*64+d]
    ushort* fT    = (ushort*)(ws + 128 * MB);    // 8MB  [b][f][c]  (fused weight, transposed)

    pack_x_k<<<2048, 256, 0, stream>>>(x, xb, 16384 * 1024 / 4);
    pack_wq_k<<<1024, 256, 0, stream>>>(w_qkv, wqb);
    trans_pack_k<<<dim3(64, 32), dim3(32, 8), 0, stream>>>(w_qkv, wkvT, 1024, 3072, 1024);
    trans_pack_k<<<dim3(32, 32), dim3(32, 8), 0, stream>>>(w_out, woutT, 1024, 1024, 0);
    // GEMM1: k,v only + fused per-head LN + transposed scatter
    gemm_bt_k<0><<<dim3(16, 128), 256, 0, stream>>>(xb, wkvT, 2048, 1024, 0, 0,
                                                    nullptr, kb, vb,
                                                    gamma_k, beta_k, gamma_v, beta_v,
                                                    nullptr, nullptr);
    hipMemsetAsync(sc, 0, 64 * 4096 * sizeof(float), stream);
    scores_k<<<dim3(8, 64), 256, 0, stream>>>(kb, vb, sc);
    wprime_k<<<dim3(8, 64), 256, 0, stream>>>(sc, woutT, wpT);
    // fold: fT[b][f][c] = sum_d wpT[b][f][d] * wqb[c][d]
    gemm_bt_k<2><<<dim3(8, 8, 4), 256, 0, stream>>>(wpT, wqb, 1024, 0, 0, (size_t)1048576,
                                                    fT, nullptr, nullptr,
                                                    nullptr, nullptr, nullptr, nullptr,
                                                    nullptr, nullptr);
    // GEMM2: out = xb · fT(b)^T + bias
    gemm_bt_k<1><<<dim3(8, 128), 256, 0, stream>>>(xb, fT, 1024, 0, (size_t)1048576, 0,
                                                   nullptr, nullptr, nullptr,
                                                   nullptr, nullptr, nullptr, nullptr,
                                                   b_out, out);
}

// Round 8
// 227.766 us; speedup vs baseline: 2.1099x; 1.0392x over previous
//
#include <hip/hip_runtime.h>

typedef __attribute__((ext_vector_type(4))) float f32x4;
typedef __attribute__((ext_vector_type(8))) short s16x8;

#define DEV static __device__ __forceinline__

typedef __attribute__((address_space(3))) void lds_t;
typedef __attribute__((address_space(1))) void gbl_t;

DEV void gload_lds16(const void* g, void* l) {
    __builtin_amdgcn_global_load_lds((gbl_t*)g, (lds_t*)l, 16, 0, 0);
}

DEV ushort f2bf(float f) {
    unsigned u = __float_as_uint(f);
    u += 0x7fffu + ((u >> 16) & 1u);   // round-to-nearest-even
    return (ushort)(u >> 16);
}
DEV float bf2f(ushort h) { return __uint_as_float(((unsigned)h) << 16); }

// raw barrier with compiler+scheduler fences (no vmcnt(0) drain, unlike __syncthreads)
#define FULLBAR() do {                              \
    __builtin_amdgcn_sched_barrier(0);              \
    asm volatile("" ::: "memory");                  \
    __builtin_amdgcn_s_barrier();                   \
    asm volatile("" ::: "memory");                  \
    __builtin_amdgcn_sched_barrier(0);              \
} while (0)

#define WAITVM(n) asm volatile("s_waitcnt vmcnt(" #n ")" ::: "memory")

// ---------------- pack x (fp32 -> bf16) ----------------
__global__ void pack_x_k(const float* __restrict__ x, ushort* __restrict__ xb, int n4) {
    int stride = gridDim.x * blockDim.x;
    for (int i = blockIdx.x * blockDim.x + threadIdx.x; i < n4; i += stride) {
        float4 v = reinterpret_cast<const float4*>(x)[i];
        ushort4 o;
        o.x = f2bf(v.x); o.y = f2bf(v.y); o.z = f2bf(v.z); o.w = f2bf(v.w);
        reinterpret_cast<ushort4*>(xb)[i] = o;
    }
}

// ---- pack Wq slice (no transpose): wqb[c][d'] = bf16(w_qkv[c][d']), d'<1024, row stride 3072 ----
__global__ void pack_wq_k(const float* __restrict__ w, ushort* __restrict__ o) {
    int i = blockIdx.x * 256 + threadIdx.x;   // over 1024*256 float4 groups
    int r = i >> 8, c4 = i & 255;
    float4 v = *reinterpret_cast<const float4*>(w + (size_t)r * 3072 + c4 * 4);
    ushort4 u;
    u.x = f2bf(v.x); u.y = f2bf(v.y); u.z = f2bf(v.z); u.w = f2bf(v.w);
    *reinterpret_cast<ushort4*>(o + (size_t)r * 1024 + c4 * 4) = u;
}

// ------- transpose + pack: in fp32 [R][C], cols col0.., -> out bf16 [C-col0][R] -------
__global__ void trans_pack_k(const float* __restrict__ in, ushort* __restrict__ out,
                             int R, int C, int col0) {
    __shared__ float tile[32][33];
    int bx = col0 + blockIdx.x * 32, by = blockIdx.y * 32;
    int tx = threadIdx.x, ty = threadIdx.y;
#pragma unroll
    for (int i = 0; i < 32; i += 8)
        tile[ty + i][tx] = in[(size_t)(by + ty + i) * C + bx + tx];
    __syncthreads();
#pragma unroll
    for (int i = 0; i < 32; i += 8)
        out[(size_t)(bx - col0 + ty + i) * R + by + tx] = f2bf(tile[tx][ty + i]);
}

// ---------------- main GEMM: C[M][Nn] = A[M][K=1024](bf16) * Bt[Nn][1024]^T (bf16), fp32 acc --------
// 128x128 tile, BK=32, 3-slot LDS ring, 2-K-tile-deep global_load_lds prefetch, counted vmcnt(8),
// raw s_barrier. XOR-swizzled 16B granules (linear LDS dest + pre-swizzled global source +
// swizzled ds_read — rule #21 pattern): granule' = g ^ ((row>>1)&3) kills the 8-way bank conflict.
// MODE 0: per-head LayerNorm fused; TRANSPOSED scatter to kT/vT [b][h][d][n] via in-LDS transpose.
// MODE 1: add bias, write fp32 to outf[M][Nn]; Bt selected per-b via b_stride (b = m0>>12).
// MODE 2: bf16 out to qo (per-b via blockIdx.z: A += z*a_bstride, qo += z*2^20), no swizzle.
template <int MODE>
__global__ __launch_bounds__(256) void gemm_bt_k(
    const ushort* __restrict__ A, const ushort* __restrict__ Bt,
    int Nn, int col0, size_t b_stride, size_t a_bstride,
    ushort* __restrict__ qo, ushort* __restrict__ ko, ushort* __restrict__ vo,
    const float* __restrict__ gk, const float* __restrict__ bk,
    const float* __restrict__ gv, const float* __restrict__ bv,
    const float* __restrict__ bias, float* __restrict__ outf)
{
    // 3 ring slots x (A 4096 + B 4096) ushorts = 48 KB. MODE-0 transpose buffer overlays (36 KB).
    __shared__ __align__(16) ushort SH[24576];
    const int t = threadIdx.x;
    const int w = t >> 6, lane = t & 63;
    const int wm = w >> 1, wn = w & 1;
    const int lrow = lane & 15, kh = lane >> 4;

    int n0, m0;
    if (MODE == 2) {
        n0 = blockIdx.x * 128; m0 = blockIdx.y * 128;
    } else {
        // bijective XCD-chunked swizzle (grid total % 8 == 0)
        int bid = blockIdx.y * gridDim.x + blockIdx.x;
        int C8 = (gridDim.x * gridDim.y) >> 3;
        int nid = (bid & 7) * C8 + (bid >> 3);
        n0 = (nid % gridDim.x) * 128;
        m0 = (nid / gridDim.x) * 128;
    }

    const ushort* Ae  = (MODE == 2) ? A + blockIdx.z * a_bstride : A;
    const ushort* Bte = (MODE == 1) ? Bt + (size_t)(m0 >> 12) * b_stride : Bt;

    const int srow0 = w * 32 + (lane >> 2);   // staging row (call 0); call 1 = +16
    // pre-swizzled global source granule: s(row) = (row>>1)&3 = (lane>>3)&3 (same for +16 call)
    const int scolSwz = (((lane & 3) ^ ((lane >> 3) & 3)) * 8);

    f32x4 acc[4][4] = {};

    // stage K-tile kt into ring slot s (4 x global_load_lds_dwordx4 per thread), LDS dest linear
    auto STAGE = [&](int kt, int s) {
        ushort* As = SH + s * 8192;
        ushort* Bs = As + 4096;
        const ushort* Ag = Ae  + (size_t)(m0 + srow0) * 1024 + kt * 32 + scolSwz;
        const ushort* Bg = Bte + (size_t)(n0 + srow0) * 1024 + kt * 32 + scolSwz;
        gload_lds16(Ag,             As + w * 1024);
        gload_lds16(Bg,             Bs + w * 1024);
        gload_lds16(Ag + 16 * 1024, As + w * 1024 + 512);
        gload_lds16(Bg + 16 * 1024, Bs + w * 1024 + 512);
    };

    // swizzled read granule: g = kh ^ ((row>>1)&3); row = *+lrow -> (lrow>>1)&3 (const per lane)
    const int gsw = (lrow >> 1) & 3;
    const int rdoff = (kh ^ gsw) * 8;

    auto COMPUTE = [&](int s) {
        const ushort* As = SH + s * 8192;
        const ushort* Bs = As + 4096;
        s16x8 af[4], bfr[4];
#pragma unroll
        for (int mi = 0; mi < 4; mi++)
            af[mi] = *reinterpret_cast<const s16x8*>(&As[(wm * 64 + mi * 16 + lrow) * 32 + rdoff]);
#pragma unroll
        for (int ni = 0; ni < 4; ni++)
            bfr[ni] = *reinterpret_cast<const s16x8*>(&Bs[(wn * 64 + ni * 16 + lrow) * 32 + rdoff]);
#pragma unroll
        for (int mi = 0; mi < 4; mi++)
#pragma unroll
            for (int ni = 0; ni < 4; ni++)
                acc[mi][ni] = __builtin_amdgcn_mfma_f32_16x16x32_bf16(af[mi], bfr[ni], acc[mi][ni], 0, 0, 0);
    };

    // prologue: 2 K-tiles in flight
    STAGE(0, 0);
    STAGE(1, 1);
    int ss = 2, sc_ = 0;    // stage slot for kt+2, compute slot for kt
    for (int kt = 0; kt < 30; ++kt) {
        STAGE(kt + 2, ss);
        ss = (ss == 2) ? 0 : ss + 1;
        WAITVM(8);          // stage(kt) landed; stage(kt+1), stage(kt+2) still in flight
        FULLBAR();
        COMPUTE(sc_);
        sc_ = (sc_ == 2) ? 0 : sc_ + 1;
        FULLBAR();
    }
    // tail: kt=30 (slot 0), kt=31 (slot 1)
    WAITVM(4); FULLBAR(); COMPUTE(0); FULLBAR();
    WAITVM(0); FULLBAR(); COMPUTE(1);

    // C/D layout (verified m89): col = lane&15, row = (lane>>4)*4 + reg
    if (MODE == 0) {
        const int e0 = col0 + n0 + wn * 64;   // aligned 64-col group == one head
        const int which = e0 >> 10;           // 1=k, 2=v
        const int h = (e0 >> 6) & 15;
        const float* g  = (which == 1) ? gk : gv;
        const float* bb = (which == 1) ? bk : bv;
        ushort* dst     = (which == 1) ? ko : vo;
        float gr[4], br[4];
#pragma unroll
        for (int ni = 0; ni < 4; ni++) {
            gr[ni] = g[h * 64 + ni * 16 + lrow];
            br[ni] = bb[h * 64 + ni * 16 + lrow];
        }
        __syncthreads();                       // staging LDS dead for ALL waves; Tl overlays
        ushort* Tl = SH + w * 4608;            // this wave's [64 d][72 pitch] transpose tile
#pragma unroll
        for (int mi = 0; mi < 4; mi++)
#pragma unroll
            for (int j = 0; j < 4; j++) {
                float s = acc[mi][0][j] + acc[mi][1][j] + acc[mi][2][j] + acc[mi][3][j];
                s += __shfl_xor(s, 1, 64);
                s += __shfl_xor(s, 2, 64);
                s += __shfl_xor(s, 4, 64);
                s += __shfl_xor(s, 8, 64);
                float mu = s * (1.f / 64.f);
                float t2 = 0.f;
#pragma unroll
                for (int ni = 0; ni < 4; ni++) {
                    float dd = acc[mi][ni][j] - mu;
                    t2 += dd * dd;
                }
                t2 += __shfl_xor(t2, 1, 64);
                t2 += __shfl_xor(t2, 2, 64);
                t2 += __shfl_xor(t2, 4, 64);
                t2 += __shfl_xor(t2, 8, 64);
                float inv = rsqrtf(t2 * (1.f / 64.f) + 1e-5f);
#pragma unroll
                for (int ni = 0; ni < 4; ni++) {
                    float y = (acc[mi][ni][j] - mu) * inv * gr[ni] + br[ni];
                    Tl[(ni * 16 + lrow) * 72 + mi * 16 + kh * 4 + j] = f2bf(y);
                }
            }
        // write out transposed: kT[b][h][d][n], coalesced 128B row chunks
        const int mrow0 = m0 + wm * 64;
        const int b = mrow0 >> 12, ns0 = mrow0 & 4095;
        ushort* obase = dst + (((size_t)b * 16 + h) * 64) * 4096 + ns0;
#pragma unroll
        for (int p = 0; p < 8; ++p) {
            int d = p * 8 + (lane >> 3);
            int mo = (lane & 7) * 8;
            s16x8 vv = *reinterpret_cast<const s16x8*>(&Tl[d * 72 + mo]);
            *reinterpret_cast<s16x8*>(obase + (size_t)d * 4096 + mo) = vv;
        }
    } else if (MODE == 1) {
#pragma unroll
        for (int mi = 0; mi < 4; mi++)
#pragma unroll
            for (int ni = 0; ni < 4; ni++) {
                int e = n0 + wn * 64 + ni * 16 + lrow;
                float bv2 = bias[e];
#pragma unroll
                for (int j = 0; j < 4; j++) {
                    int m = m0 + wm * 64 + mi * 16 + kh * 4 + j;
                    outf[(size_t)m * Nn + e] = acc[mi][ni][j] + bv2;
                }
            }
    } else {
        ushort* o = qo + (size_t)blockIdx.z * 1048576;
#pragma unroll
        for (int mi = 0; mi < 4; mi++)
#pragma unroll
            for (int ni = 0; ni < 4; ni++) {
                int e = n0 + wn * 64 + ni * 16 + lrow;
#pragma unroll
                for (int j = 0; j < 4; j++) {
                    int m = m0 + wm * 64 + mi * 16 + kh * 4 + j;
                    o[(size_t)m * 1024 + e] = f2bf(acc[mi][ni][j]);
                }
            }
    }
}

// ---- scores[bh][d][e] = sum_n kT[bh][d][n]*vT[bh][e][n] / 4096, MFMA, fp32 atomics ----
// kT/vT: [b][h][d=64][n=4096] bf16. grid (8, 64); wave reduces 128 n (4 K-steps).
__global__ __launch_bounds__(256) void scores_k(const ushort* __restrict__ kT,
                                                const ushort* __restrict__ vT,
                                                float* __restrict__ sc)
{
    __shared__ float red[4][64][65];
    const int bh = blockIdx.y;
    const int t = threadIdx.x;
    const int w = t >> 6, lane = t & 63;
    const int lrow = lane & 15, kh = lane >> 4;
    const ushort* ka = kT + (size_t)bh * 64 * 4096;
    const ushort* va = vT + (size_t)bh * 64 * 4096;
    const int n0 = blockIdx.x * 512 + w * 128;

    f32x4 acc[4][4] = {};
#pragma unroll
    for (int ks = 0; ks < 4; ++ks) {
        const int n = n0 + ks * 32 + kh * 8;
        s16x8 af[4], bfr[4];
#pragma unroll
        for (int mi = 0; mi < 4; mi++)
            af[mi] = *reinterpret_cast<const s16x8*>(ka + (size_t)(mi * 16 + lrow) * 4096 + n);
#pragma unroll
        for (int ni = 0; ni < 4; ni++)
            bfr[ni] = *reinterpret_cast<const s16x8*>(va + (size_t)(ni * 16 + lrow) * 4096 + n);
#pragma unroll
        for (int mi = 0; mi < 4; mi++)
#pragma unroll
            for (int ni = 0; ni < 4; ni++)
                acc[mi][ni] = __builtin_amdgcn_mfma_f32_16x16x32_bf16(af[mi], bfr[ni], acc[mi][ni], 0, 0, 0);
    }
    // C layout: row d = mi*16+kh*4+j, col e = ni*16+lrow
#pragma unroll
    for (int mi = 0; mi < 4; mi++)
#pragma unroll
        for (int ni = 0; ni < 4; ni++)
#pragma unroll
            for (int j = 0; j < 4; j++)
                red[w][mi * 16 + kh * 4 + j][ni * 16 + lrow] = acc[mi][ni][j];
    __syncthreads();
    const float scale = 1.f / 4096.f;
    for (int idx = t; idx < 4096; idx += 256) {
        int d = idx >> 6, e = idx & 63;
        float s = red[0][d][e] + red[1][d][e] + red[2][d][e] + red[3][d][e];
        atomicAdd(&sc[(size_t)bh * 4096 + idx], s * scale);
    }
}

// -------- W'T[b][f][h*64+d] = sum_e woutT[f][h*64+e] * sc[b*16+h][d][e], bf16 out --------
__global__ __launch_bounds__(256) void wprime_k(const float* __restrict__ sc,
                                                const ushort* __restrict__ woutT,
                                                ushort* __restrict__ wpT)
{
    __shared__ float scl[64][65];      // [e][d], padded
    __shared__ ushort wl[128][72];     // [f_local][e], padded
    int bh = blockIdx.y;
    int b = bh >> 4, h = bh & 15;
    int f0 = blockIdx.x * 128;
    int t = threadIdx.x;
    for (int i = t; i < 4096; i += 256) {
        int d2 = i >> 6, e = i & 63;
        scl[e][d2] = sc[(size_t)bh * 4096 + i];
    }
    for (int i = t; i < 1024; i += 256) {
        int fl = i >> 3, c = i & 7;
        *reinterpret_cast<int4*>(&wl[fl][c * 8]) =
            *reinterpret_cast<const int4*>(woutT + (size_t)(f0 + fl) * 1024 + h * 64 + c * 8);
    }
    __syncthreads();
    int dd = (t & 7) * 8;
    int fl0 = t >> 3;
#pragma unroll
    for (int fi = 0; fi < 4; ++fi) {
        int fl = fi * 32 + fl0;
        float acc[8] = {};
        for (int e = 0; e < 64; ++e) {
            float wv = bf2f(wl[fl][e]);
#pragma unroll
            for (int i = 0; i < 8; ++i)
                acc[i] = fmaf(wv, scl[e][dd + i], acc[i]);
        }
        ushort4 o0, o1;
        o0.x = f2bf(acc[0]); o0.y = f2bf(acc[1]); o0.z = f2bf(acc[2]); o0.w = f2bf(acc[3]);
        o1.x = f2bf(acc[4]); o1.y = f2bf(acc[5]); o1.z = f2bf(acc[6]); o1.w = f2bf(acc[7]);
        ushort* op = wpT + ((size_t)b * 1024 + f0 + fl) * 1024 + h * 64 + dd;
        *reinterpret_cast<ushort4*>(op) = o0;
        *reinterpret_cast<ushort4*>(op + 4) = o1;
    }
}

extern "C" void kernel_launch(void* const* d_in, const int* in_sizes, int n_in,
                              void* d_out, int out_size, void* d_ws, size_t ws_size,
                              hipStream_t stream)
{
    const float* x       = (const float*)d_in[0];
    const float* w_qkv   = (const float*)d_in[1];
    const float* gamma_k = (const float*)d_in[2];
    const float* beta_k  = (const float*)d_in[3];
    const float* gamma_v = (const float*)d_in[4];
    const float* beta_v  = (const float*)d_in[5];
    const float* w_out   = (const float*)d_in[6];
    const float* b_out   = (const float*)d_in[7];
    float* out = (float*)d_out;

    char* ws = (char*)d_ws;
    const size_t MB = 1024 * 1024;
    ushort* xb    = (ushort*)(ws);               // 32MB [m][1024] (alive through GEMM2)
    ushort* wkvT  = (ushort*)(ws + 32 * MB);     // 4MB  [2048][1024] (k,v cols of w_qkv, transposed)
    ushort* woutT = (ushort*)(ws + 38 * MB);     // 2MB  [1024][1024]
    ushort* wqb   = (ushort*)(ws + 40 * MB);     // 2MB  [c][1024] (q cols of w_qkv, row-major)
    ushort* kb    = (ushort*)(ws + 48 * MB);     // 32MB [b][h][d][n]  (kT)
    ushort* vb    = (ushort*)(ws + 80 * MB);     // 32MB [b][h][d][n]  (vT)
    float*  sc    = (float*)(ws + 112 * MB);     // 1MB  [bh][d][e]
    ushort* wpT   = (ushort*)(ws + 120 * MB);    // 8MB  [b][f][h*64+d]
    ushort* fT    = (ushort*)(ws + 128 * MB);    // 8MB  [b][f][c]  (fused weight, transposed)

    pack_x_k<<<2048, 256, 0, stream>>>(x, xb, 16384 * 1024 / 4);
    pack_wq_k<<<1024, 256, 0, stream>>>(w_qkv, wqb);
    trans_pack_k<<<dim3(64, 32), dim3(32, 8), 0, stream>>>(w_qkv, wkvT, 1024, 3072, 1024);
    trans_pack_k<<<dim3(32, 32), dim3(32, 8), 0, stream>>>(w_out, woutT, 1024, 1024, 0);
    // GEMM1: k,v only + fused per-head LN + transposed scatter
    gemm_bt_k<0><<<dim3(16, 128), 256, 0, stream>>>(xb, wkvT, 2048, 1024, 0, 0,
                                                    nullptr, kb, vb,
                                                    gamma_k, beta_k, gamma_v, beta_v,
                                                    nullptr, nullptr);
    hipMemsetAsync(sc, 0, 64 * 4096 * sizeof(float), stream);
    scores_k<<<dim3(8, 64), 256, 0, stream>>>(kb, vb, sc);
    wprime_k<<<dim3(8, 64), 256, 0, stream>>>(sc, woutT, wpT);
    // fold: fT[b][f][c] = sum_d wpT[b][f][d] * wqb[c][d]
    gemm_bt_k<2><<<dim3(8, 8, 4), 256, 0, stream>>>(wpT, wqb, 1024, 0, 0, (size_t)1048576,
                                                    fT, nullptr, nullptr,
                                                    nullptr, nullptr, nullptr, nullptr,
                                                    nullptr, nullptr);
    // GEMM2: out = xb · fT(b)^T + bias
    gemm_bt_k<1><<<dim3(8, 128), 256, 0, stream>>>(xb, fT, 1024, 0, (size_t)1048576, 0,
                                                   nullptr, nullptr, nullptr,
                                                   nullptr, nullptr, nullptr, nullptr,
                                                   b_out, out);
}

// Round 9
// 224.419 us; speedup vs baseline: 2.1413x; 1.0149x over previous
//
#include <hip/hip_runtime.h>

typedef __attribute__((ext_vector_type(4))) float f32x4;
typedef __attribute__((ext_vector_type(8))) short s16x8;

#define DEV static __device__ __forceinline__

typedef __attribute__((address_space(3))) void lds_t;
typedef __attribute__((address_space(1))) void gbl_t;

DEV void gload_lds16(const void* g, void* l) {
    __builtin_amdgcn_global_load_lds((gbl_t*)g, (lds_t*)l, 16, 0, 0);
}

DEV ushort f2bf(float f) {
    unsigned u = __float_as_uint(f);
    u += 0x7fffu + ((u >> 16) & 1u);   // round-to-nearest-even
    return (ushort)(u >> 16);
}
DEV float bf2f(ushort h) { return __uint_as_float(((unsigned)h) << 16); }

// raw barrier with compiler+scheduler fences (no vmcnt(0) drain, unlike __syncthreads)
#define FULLBAR() do {                              \
    __builtin_amdgcn_sched_barrier(0);              \
    asm volatile("" ::: "memory");                  \
    __builtin_amdgcn_s_barrier();                   \
    asm volatile("" ::: "memory");                  \
    __builtin_amdgcn_sched_barrier(0);              \
} while (0)

#define WAITVM(n) asm volatile("s_waitcnt vmcnt(" #n ")" ::: "memory")

// ---------------- pack x (fp32 -> bf16) ----------------
__global__ void pack_x_k(const float* __restrict__ x, ushort* __restrict__ xb, int n4) {
    int stride = gridDim.x * blockDim.x;
    for (int i = blockIdx.x * blockDim.x + threadIdx.x; i < n4; i += stride) {
        float4 v = reinterpret_cast<const float4*>(x)[i];
        ushort4 o;
        o.x = f2bf(v.x); o.y = f2bf(v.y); o.z = f2bf(v.z); o.w = f2bf(v.w);
        reinterpret_cast<ushort4*>(xb)[i] = o;
    }
}

// ---- pack Wq slice (no transpose): wqb[c][d'] = bf16(w_qkv[c][d']), d'<1024, row stride 3072 ----
__global__ void pack_wq_k(const float* __restrict__ w, ushort* __restrict__ o) {
    int i = blockIdx.x * 256 + threadIdx.x;   // over 1024*256 float4 groups
    int r = i >> 8, c4 = i & 255;
    float4 v = *reinterpret_cast<const float4*>(w + (size_t)r * 3072 + c4 * 4);
    ushort4 u;
    u.x = f2bf(v.x); u.y = f2bf(v.y); u.z = f2bf(v.z); u.w = f2bf(v.w);
    *reinterpret_cast<ushort4*>(o + (size_t)r * 1024 + c4 * 4) = u;
}

// ------- transpose + pack: in fp32 [R][C], cols col0.., -> out bf16 [C-col0][R] -------
__global__ void trans_pack_k(const float* __restrict__ in, ushort* __restrict__ out,
                             int R, int C, int col0) {
    __shared__ float tile[32][33];
    int bx = col0 + blockIdx.x * 32, by = blockIdx.y * 32;
    int tx = threadIdx.x, ty = threadIdx.y;
#pragma unroll
    for (int i = 0; i < 32; i += 8)
        tile[ty + i][tx] = in[(size_t)(by + ty + i) * C + bx + tx];
    __syncthreads();
#pragma unroll
    for (int i = 0; i < 32; i += 8)
        out[(size_t)(bx - col0 + ty + i) * R + by + tx] = f2bf(tile[tx][ty + i]);
}

// ---------------- main GEMM: C[M][Nn] = A[M][K=1024](bf16) * Bt[Nn][1024]^T (bf16), fp32 acc --------
// 128x256 block tile, per-wave 64x128 (4 A-frags x 8 B-frags = 32 MFMA/K-step), BK=32,
// 3-slot LDS ring (72 KB), 2-K-tile-deep prefetch, counted vmcnt(12), raw s_barrier,
// XOR-swizzled 16B granules (linear LDS dest + pre-swizzled source + swizzled read).
// MODE 0: per-head LayerNorm fused (2 heads per wave); TRANSPOSED scatter to kT/vT [b][h][d][n].
// MODE 1: add bias, write fp32 to outf[M][Nn]; Bt selected per-b via b_stride (b = m0>>12).
// MODE 2: bf16 out to qo (per-b via blockIdx.z: A += z*a_bstride, qo += z*2^20), no swizzle.
template <int MODE>
__global__ __launch_bounds__(256, 2) void gemm_bt_k(
    const ushort* __restrict__ A, const ushort* __restrict__ Bt,
    int Nn, int col0, size_t b_stride, size_t a_bstride,
    ushort* __restrict__ qo, ushort* __restrict__ ko, ushort* __restrict__ vo,
    const float* __restrict__ gk, const float* __restrict__ bk,
    const float* __restrict__ gv, const float* __restrict__ bv,
    const float* __restrict__ bias, float* __restrict__ outf)
{
    // 3 ring slots x (A 4096 + B 8192 ushorts) = 72 KB. MODE-0 transpose buffer overlays (72 KB).
    __shared__ __align__(16) ushort SH[36864];
    const int t = threadIdx.x;
    const int w = t >> 6, lane = t & 63;
    const int wm = w >> 1, wn = w & 1;
    const int lrow = lane & 15, kh = lane >> 4;

    int n0, m0;
    if (MODE == 2) {
        n0 = blockIdx.x * 256; m0 = blockIdx.y * 128;
    } else {
        // bijective XCD-chunked swizzle (grid total % 8 == 0)
        int bid = blockIdx.y * gridDim.x + blockIdx.x;
        int C8 = (gridDim.x * gridDim.y) >> 3;
        int nid = (bid & 7) * C8 + (bid >> 3);
        n0 = (nid % gridDim.x) * 256;
        m0 = (nid / gridDim.x) * 128;
    }

    const ushort* Ae  = (MODE == 2) ? A + blockIdx.z * a_bstride : A;
    const ushort* Bte = (MODE == 1) ? Bt + (size_t)(m0 >> 12) * b_stride : Bt;

    const int srow = lane >> 2;               // staging row within 16-row group
    // pre-swizzled global source granule: s(row) = (row>>1)&3 = (lane>>3)&3 for all calls
    const int scolSwz = (((lane & 3) ^ ((lane >> 3) & 3)) * 8);

    f32x4 acc[4][8] = {};

    // stage K-tile kt into ring slot s (6 x global_load_lds_dwordx4 per thread), LDS dest linear
    auto STAGE = [&](int kt, int s) {
        ushort* As = SH + s * 12288;
        ushort* Bs = As + 4096;
        const ushort* Ag = Ae  + (size_t)(m0 + w * 16 + srow) * 1024 + kt * 32 + scolSwz;
        const ushort* Bg = Bte + (size_t)(n0 + w * 16 + srow) * 1024 + kt * 32 + scolSwz;
        gload_lds16(Ag,              As + w * 512);
        gload_lds16(Ag + 64 * 1024,  As + w * 512 + 2048);
        gload_lds16(Bg,              Bs + w * 512);
        gload_lds16(Bg + 64 * 1024,  Bs + w * 512 + 2048);
        gload_lds16(Bg + 128 * 1024, Bs + w * 512 + 4096);
        gload_lds16(Bg + 192 * 1024, Bs + w * 512 + 6144);
    };

    // swizzled read granule: g = kh ^ ((fragrow>>1)&3) = kh ^ ((lrow>>1)&3) (const per lane)
    const int rdoff = (kh ^ ((lrow >> 1) & 3)) * 8;

    auto COMPUTE = [&](int s) {
        const ushort* As = SH + s * 12288;
        const ushort* Bs = As + 4096;
        s16x8 af[4], bfr[8];
#pragma unroll
        for (int mi = 0; mi < 4; mi++)
            af[mi] = *reinterpret_cast<const s16x8*>(&As[(wm * 64 + mi * 16 + lrow) * 32 + rdoff]);
#pragma unroll
        for (int ni = 0; ni < 8; ni++)
            bfr[ni] = *reinterpret_cast<const s16x8*>(&Bs[(wn * 128 + ni * 16 + lrow) * 32 + rdoff]);
#pragma unroll
        for (int mi = 0; mi < 4; mi++)
#pragma unroll
            for (int ni = 0; ni < 8; ni++)
                acc[mi][ni] = __builtin_amdgcn_mfma_f32_16x16x32_bf16(af[mi], bfr[ni], acc[mi][ni], 0, 0, 0);
    };

    // prologue: 2 K-tiles in flight (slot = kt % 3)
    STAGE(0, 0);
    STAGE(1, 1);
    int ss = 2, sc_ = 0;
    for (int kt = 0; kt < 30; ++kt) {
        STAGE(kt + 2, ss);
        ss = (ss == 2) ? 0 : ss + 1;
        WAITVM(12);         // stage(kt) landed; stage(kt+1), stage(kt+2) still in flight
        FULLBAR();
        COMPUTE(sc_);
        sc_ = (sc_ == 2) ? 0 : sc_ + 1;
        FULLBAR();
    }
    // tail: kt=30 (slot 0), kt=31 (slot 1)
    WAITVM(6); FULLBAR(); COMPUTE(0); FULLBAR();
    WAITVM(0); FULLBAR(); COMPUTE(1);

    // C/D layout (verified m89): col = lane&15, row = (lane>>4)*4 + reg
    if (MODE == 0) {
        const int e0 = col0 + n0 + wn * 128;  // wave's 128-col span = 2 aligned heads
        const int which = e0 >> 10;           // 1=k, 2=v (span never straddles)
        const int h0 = (e0 >> 6) & 15;
        const float* g  = (which == 1) ? gk : gv;
        const float* bb = (which == 1) ? bk : bv;
        ushort* dst     = (which == 1) ? ko : vo;
        float gr[8], br[8];
#pragma unroll
        for (int ni = 0; ni < 8; ni++) {
            int gi = (h0 + (ni >> 2)) * 64 + (ni & 3) * 16 + lrow;
            gr[ni] = g[gi];
            br[ni] = bb[gi];
        }
        __syncthreads();                       // staging LDS dead for ALL waves; Tl overlays
        ushort* Tl = SH + w * 9216;            // this wave's [128 d'][72 pitch] transpose tile
#pragma unroll
        for (int mi = 0; mi < 4; mi++)
#pragma unroll
            for (int j = 0; j < 4; j++) {
                // head 0: ni 0..3
                float s0 = acc[mi][0][j] + acc[mi][1][j] + acc[mi][2][j] + acc[mi][3][j];
                s0 += __shfl_xor(s0, 1, 64);
                s0 += __shfl_xor(s0, 2, 64);
                s0 += __shfl_xor(s0, 4, 64);
                s0 += __shfl_xor(s0, 8, 64);
                float mu0 = s0 * (1.f / 64.f);
                float t0 = 0.f;
#pragma unroll
                for (int ni = 0; ni < 4; ni++) {
                    float dd = acc[mi][ni][j] - mu0;
                    t0 += dd * dd;
                }
                t0 += __shfl_xor(t0, 1, 64);
                t0 += __shfl_xor(t0, 2, 64);
                t0 += __shfl_xor(t0, 4, 64);
                t0 += __shfl_xor(t0, 8, 64);
                float inv0 = rsqrtf(t0 * (1.f / 64.f) + 1e-5f);
                // head 1: ni 4..7
                float s1 = acc[mi][4][j] + acc[mi][5][j] + acc[mi][6][j] + acc[mi][7][j];
                s1 += __shfl_xor(s1, 1, 64);
                s1 += __shfl_xor(s1, 2, 64);
                s1 += __shfl_xor(s1, 4, 64);
                s1 += __shfl_xor(s1, 8, 64);
                float mu1 = s1 * (1.f / 64.f);
                float t1 = 0.f;
#pragma unroll
                for (int ni = 4; ni < 8; ni++) {
                    float dd = acc[mi][ni][j] - mu1;
                    t1 += dd * dd;
                }
                t1 += __shfl_xor(t1, 1, 64);
                t1 += __shfl_xor(t1, 2, 64);
                t1 += __shfl_xor(t1, 4, 64);
                t1 += __shfl_xor(t1, 8, 64);
                float inv1 = rsqrtf(t1 * (1.f / 64.f) + 1e-5f);
#pragma unroll
                for (int ni = 0; ni < 8; ni++) {
                    float mu = (ni < 4) ? mu0 : mu1;
                    float inv = (ni < 4) ? inv0 : inv1;
                    float y = (acc[mi][ni][j] - mu) * inv * gr[ni] + br[ni];
                    Tl[(ni * 16 + lrow) * 72 + mi * 16 + kh * 4 + j] = f2bf(y);
                }
            }
        // write out transposed: kT[b][h][d][n], coalesced 128B row chunks, 2 heads
        const int mrow0 = m0 + wm * 64;
        const int b = mrow0 >> 12, ns0 = mrow0 & 4095;
#pragma unroll
        for (int hh = 0; hh < 2; ++hh) {
            ushort* obase = dst + (((size_t)b * 16 + h0 + hh) * 64) * 4096 + ns0;
#pragma unroll
            for (int p = 0; p < 8; ++p) {
                int d = p * 8 + (lane >> 3);
                int mo = (lane & 7) * 8;
                s16x8 vv = *reinterpret_cast<const s16x8*>(&Tl[(hh * 64 + d) * 72 + mo]);
                *reinterpret_cast<s16x8*>(obase + (size_t)d * 4096 + mo) = vv;
            }
        }
    } else if (MODE == 1) {
#pragma unroll
        for (int mi = 0; mi < 4; mi++)
#pragma unroll
            for (int ni = 0; ni < 8; ni++) {
                int e = n0 + wn * 128 + ni * 16 + lrow;
                float bv2 = bias[e];
#pragma unroll
                for (int j = 0; j < 4; j++) {
                    int m = m0 + wm * 64 + mi * 16 + kh * 4 + j;
                    outf[(size_t)m * Nn + e] = acc[mi][ni][j] + bv2;
                }
            }
    } else {
        ushort* o = qo + (size_t)blockIdx.z * 1048576;
#pragma unroll
        for (int mi = 0; mi < 4; mi++)
#pragma unroll
            for (int ni = 0; ni < 8; ni++) {
                int e = n0 + wn * 128 + ni * 16 + lrow;
#pragma unroll
                for (int j = 0; j < 4; j++) {
                    int m = m0 + wm * 64 + mi * 16 + kh * 4 + j;
                    o[(size_t)m * 1024 + e] = f2bf(acc[mi][ni][j]);
                }
            }
    }
}

// ---- scores[bh][d][e] = sum_n kT[bh][d][n]*vT[bh][e][n] / 4096, MFMA, fp32 atomics ----
// kT/vT: [b][h][d=64][n=4096] bf16. grid (8, 64); wave reduces 128 n (4 K-steps).
__global__ __launch_bounds__(256) void scores_k(const ushort* __restrict__ kT,
                                                const ushort* __restrict__ vT,
                                                float* __restrict__ sc)
{
    __shared__ float red[4][64][65];
    const int bh = blockIdx.y;
    const int t = threadIdx.x;
    const int w = t >> 6, lane = t & 63;
    const int lrow = lane & 15, kh = lane >> 4;
    const ushort* ka = kT + (size_t)bh * 64 * 4096;
    const ushort* va = vT + (size_t)bh * 64 * 4096;
    const int n0 = blockIdx.x * 512 + w * 128;

    f32x4 acc[4][4] = {};
#pragma unroll
    for (int ks = 0; ks < 4; ++ks) {
        const int n = n0 + ks * 32 + kh * 8;
        s16x8 af[4], bfr[4];
#pragma unroll
        for (int mi = 0; mi < 4; mi++)
            af[mi] = *reinterpret_cast<const s16x8*>(ka + (size_t)(mi * 16 + lrow) * 4096 + n);
#pragma unroll
        for (int ni = 0; ni < 4; ni++)
            bfr[ni] = *reinterpret_cast<const s16x8*>(va + (size_t)(ni * 16 + lrow) * 4096 + n);
#pragma unroll
        for (int mi = 0; mi < 4; mi++)
#pragma unroll
            for (int ni = 0; ni < 4; ni++)
                acc[mi][ni] = __builtin_amdgcn_mfma_f32_16x16x32_bf16(af[mi], bfr[ni], acc[mi][ni], 0, 0, 0);
    }
    // C layout: row d = mi*16+kh*4+j, col e = ni*16+lrow
#pragma unroll
    for (int mi = 0; mi < 4; mi++)
#pragma unroll
        for (int ni = 0; ni < 4; ni++)
#pragma unroll
            for (int j = 0; j < 4; j++)
                red[w][mi * 16 + kh * 4 + j][ni * 16 + lrow] = acc[mi][ni][j];
    __syncthreads();
    const float scale = 1.f / 4096.f;
    for (int idx = t; idx < 4096; idx += 256) {
        int d = idx >> 6, e = idx & 63;
        float s = red[0][d][e] + red[1][d][e] + red[2][d][e] + red[3][d][e];
        atomicAdd(&sc[(size_t)bh * 4096 + idx], s * scale);
    }
}

// -------- W'T[b][f][h*64+d] = sum_e woutT[f][h*64+e] * sc[b*16+h][d][e], bf16 out --------
__global__ __launch_bounds__(256) void wprime_k(const float* __restrict__ sc,
                                                const ushort* __restrict__ woutT,
                                                ushort* __restrict__ wpT)
{
    __shared__ float scl[64][65];      // [e][d], padded
    __shared__ ushort wl[128][72];     // [f_local][e], padded
    int bh = blockIdx.y;
    int b = bh >> 4, h = bh & 15;
    int f0 = blockIdx.x * 128;
    int t = threadIdx.x;
    for (int i = t; i < 4096; i += 256) {
        int d2 = i >> 6, e = i & 63;
        scl[e][d2] = sc[(size_t)bh * 4096 + i];
    }
    for (int i = t; i < 1024; i += 256) {
        int fl = i >> 3, c = i & 7;
        *reinterpret_cast<int4*>(&wl[fl][c * 8]) =
            *reinterpret_cast<const int4*>(woutT + (size_t)(f0 + fl) * 1024 + h * 64 + c * 8);
    }
    __syncthreads();
    int dd = (t & 7) * 8;
    int fl0 = t >> 3;
#pragma unroll
    for (int fi = 0; fi < 4; ++fi) {
        int fl = fi * 32 + fl0;
        float acc[8] = {};
        for (int e = 0; e < 64; ++e) {
            float wv = bf2f(wl[fl][e]);
#pragma unroll
            for (int i = 0; i < 8; ++i)
                acc[i] = fmaf(wv, scl[e][dd + i], acc[i]);
        }
        ushort4 o0, o1;
        o0.x = f2bf(acc[0]); o0.y = f2bf(acc[1]); o0.z = f2bf(acc[2]); o0.w = f2bf(acc[3]);
        o1.x = f2bf(acc[4]); o1.y = f2bf(acc[5]); o1.z = f2bf(acc[6]); o1.w = f2bf(acc[7]);
        ushort* op = wpT + ((size_t)b * 1024 + f0 + fl) * 1024 + h * 64 + dd;
        *reinterpret_cast<ushort4*>(op) = o0;
        *reinterpret_cast<ushort4*>(op + 4) = o1;
    }
}

extern "C" void kernel_launch(void* const* d_in, const int* in_sizes, int n_in,
                              void* d_out, int out_size, void* d_ws, size_t ws_size,
                              hipStream_t stream)
{
    const float* x       = (const float*)d_in[0];
    const float* w_qkv   = (const float*)d_in[1];
    const float* gamma_k = (const float*)d_in[2];
    const float* beta_k  = (const float*)d_in[3];
    const float* gamma_v = (const float*)d_in[4];
    const float* beta_v  = (const float*)d_in[5];
    const float* w_out   = (const float*)d_in[6];
    const float* b_out   = (const float*)d_in[7];
    float* out = (float*)d_out;

    char* ws = (char*)d_ws;
    const size_t MB = 1024 * 1024;
    ushort* xb    = (ushort*)(ws);               // 32MB [m][1024] (alive through GEMM2)
    ushort* wkvT  = (ushort*)(ws + 32 * MB);     // 4MB  [2048][1024] (k,v cols of w_qkv, transposed)
    ushort* woutT = (ushort*)(ws + 38 * MB);     // 2MB  [1024][1024]
    ushort* wqb   = (ushort*)(ws + 40 * MB);     // 2MB  [c][1024] (q cols of w_qkv, row-major)
    ushort* kb    = (ushort*)(ws + 48 * MB);     // 32MB [b][h][d][n]  (kT)
    ushort* vb    = (ushort*)(ws + 80 * MB);     // 32MB [b][h][d][n]  (vT)
    float*  sc    = (float*)(ws + 112 * MB);     // 1MB  [bh][d][e]
    ushort* wpT   = (ushort*)(ws + 120 * MB);    // 8MB  [b][f][h*64+d]
    ushort* fT    = (ushort*)(ws + 128 * MB);    // 8MB  [b][f][c]  (fused weight, transposed)

    pack_x_k<<<2048, 256, 0, stream>>>(x, xb, 16384 * 1024 / 4);
    pack_wq_k<<<1024, 256, 0, stream>>>(w_qkv, wqb);
    trans_pack_k<<<dim3(64, 32), dim3(32, 8), 0, stream>>>(w_qkv, wkvT, 1024, 3072, 1024);
    trans_pack_k<<<dim3(32, 32), dim3(32, 8), 0, stream>>>(w_out, woutT, 1024, 1024, 0);
    // GEMM1: k,v only + fused per-head LN + transposed scatter (tile 128x256)
    gemm_bt_k<0><<<dim3(8, 128), 256, 0, stream>>>(xb, wkvT, 2048, 1024, 0, 0,
                                                   nullptr, kb, vb,
                                                   gamma_k, beta_k, gamma_v, beta_v,
                                                   nullptr, nullptr);
    hipMemsetAsync(sc, 0, 64 * 4096 * sizeof(float), stream);
    scores_k<<<dim3(8, 64), 256, 0, stream>>>(kb, vb, sc);
    wprime_k<<<dim3(8, 64), 256, 0, stream>>>(sc, woutT, wpT);
    // fold: fT[b][f][c] = sum_d wpT[b][f][d] * wqb[c][d]
    gemm_bt_k<2><<<dim3(4, 8, 4), 256, 0, stream>>>(wpT, wqb, 1024, 0, 0, (size_t)1048576,
                                                    fT, nullptr, nullptr,
                                                    nullptr, nullptr, nullptr, nullptr,
                                                    nullptr, nullptr);
    // GEMM2: out = xb · fT(b)^T + bias
    gemm_bt_k<1><<<dim3(4, 128), 256, 0, stream>>>(xb, fT, 1024, 0, (size_t)1048576, 0,
                                                   nullptr, nullptr, nullptr,
                                                   nullptr, nullptr, nullptr, nullptr,
                                                   b_out, out);
}